// Round 1
// baseline (3061.006 us; speedup 1.0000x reference)
//
#include <hip/hip_runtime.h>
#include <cmath>

// Poincare-ball causal transformer forward, fp32, MI355X.
// Shapes fixed by the reference.
#define B_ 2
#define S_ 1024
#define D_ 512
#define H_ 8
#define HD_ 64
#define FF_ 2048
#define L_ 4
#define N_ (B_*S_)          // 2048 token rows
#define BHS_ (B_*H_*S_)     // 16384 head rows
#define EPSf 1e-7f
#define EPS2f 1e-14f
#define MAXNf 0.999f
#define KS_ 4               // split-K factor for M=512 GEMMs (fills 1024 blocks)

// ---------------- small helpers ----------------
struct F8 { float v[8]; };

__device__ __forceinline__ F8 ld8(const float* __restrict__ p){
  F8 r; const float4 a = *(const float4*)p; const float4 b = *(const float4*)(p+4);
  r.v[0]=a.x; r.v[1]=a.y; r.v[2]=a.z; r.v[3]=a.w;
  r.v[4]=b.x; r.v[5]=b.y; r.v[6]=b.z; r.v[7]=b.w;
  return r;
}
__device__ __forceinline__ void st8(float* __restrict__ p, const F8& r){
  *(float4*)p     = make_float4(r.v[0],r.v[1],r.v[2],r.v[3]);
  *(float4*)(p+4) = make_float4(r.v[4],r.v[5],r.v[6],r.v[7]);
}
__device__ __forceinline__ float ssq8(const F8& r){
  float s=0.f;
#pragma unroll
  for(int i=0;i<8;i++) s = fmaf(r.v[i], r.v[i], s);
  return s;
}
__device__ __forceinline__ float sum8(const F8& r){
  float s=0.f;
#pragma unroll
  for(int i=0;i<8;i++) s += r.v[i];
  return s;
}
// full-wave (64 lane) reduction
__device__ __forceinline__ float wredsum(float v){
#pragma unroll
  for(int o=1;o<64;o<<=1) v += __shfl_xor(v,o,64);
  return v;
}
// 8-lane-group reduction (one head = 8 lanes x 8 elems)
__device__ __forceinline__ float g8sum(float v){
#pragma unroll
  for(int o=1;o<8;o<<=1) v += __shfl_xor(v,o,64);
  return v;
}

// mobius_add on a D=512 row distributed over one wave (8 elems/lane)
__device__ __forceinline__ F8 mobius_add8(const F8& x, const F8& y){
  float x2 = wredsum(ssq8(x));
  float y2 = wredsum(ssq8(y));
  float d = 0.f;
#pragma unroll
  for(int i=0;i<8;i++) d = fmaf(x.v[i], y.v[i], d);
  float xy = wredsum(d);
  float cx  = 1.f + 2.f*xy + y2;
  float cy  = 1.f - x2;
  float den = fmaxf(1.f + 2.f*xy + x2*y2, EPSf);
  F8 z;
#pragma unroll
  for(int i=0;i<8;i++) z.v[i] = (cx*x.v[i] + cy*y.v[i]) / den;
  float s2 = wredsum(ssq8(z));
  float n  = sqrtf(fmaxf(s2, EPS2f));
  float pr = fminf(1.f, MAXNf/n);
#pragma unroll
  for(int i=0;i<8;i++) z.v[i] *= pr;
  return z;
}

// ---------------- kernels ----------------

// x = mobius_add(x_in, pos_tab[s])    (wave per row)
__global__ void k_mobius_pos(const float* __restrict__ xin, const float* __restrict__ pos,
                             float* __restrict__ xout){
  const int r = blockIdx.x, lane = threadIdx.x;
  const int s = r % S_;
  const size_t o = (size_t)r*D_ + (lane<<3);
  F8 x = ld8(xin + o);
  F8 y = ld8(pos + (size_t)s*D_ + (lane<<3));
  F8 z = mobius_add8(x, y);
  st8(xout + o, z);
}

// u = sum_ks partials; h = expmap0(u); x = mobius_add(x, h)   (residual, in-place on x)
__global__ void k_mobius_epi(const float* __restrict__ up, float* __restrict__ x){
  const int r = blockIdx.x, lane = threadIdx.x;
  const size_t o = (size_t)r*D_ + (lane<<3);
  F8 u = ld8(up + o);
  for(int ks=1; ks<KS_; ks++){
    F8 t = ld8(up + (size_t)ks*N_*D_ + o);
#pragma unroll
    for(int i=0;i<8;i++) u.v[i] += t.v[i];
  }
  float s2 = wredsum(ssq8(u));
  float n  = sqrtf(fmaxf(s2, EPS2f));
  float se = tanhf(n)/n;
#pragma unroll
  for(int i=0;i<8;i++) u.v[i] *= se;     // h = expmap0(u)
  F8 xv = ld8(x + o);
  F8 z = mobius_add8(xv, u);
  st8(x + o, z);
}

// fused pln -> tangent:  t = logmap0( expmap0( LN(logmap0(x))*w + b ) )
__global__ void k_pln_tan(const float* __restrict__ xin, const float* __restrict__ w,
                          const float* __restrict__ b, float* __restrict__ tout){
  const int r = blockIdx.x, lane = threadIdx.x;
  const size_t o = (size_t)r*D_ + (lane<<3);
  F8 x = ld8(xin + o);
  float s2 = wredsum(ssq8(x));
  float n  = sqrtf(fmaxf(s2, EPS2f));
  float nc = fminf(fmaxf(n, EPSf), MAXNf);
  float a  = atanhf(nc)/nc;
  F8 t;
#pragma unroll
  for(int i=0;i<8;i++) t.v[i] = x.v[i]*a;
  float mu = wredsum(sum8(t)) * (1.f/(float)D_);
#pragma unroll
  for(int i=0;i<8;i++) t.v[i] -= mu;
  float var = wredsum(ssq8(t)) * (1.f/(float)D_);
  float inv = 1.f/sqrtf(var + 1e-5f);
  F8 wv = ld8(w + (lane<<3));
  F8 bv = ld8(b + (lane<<3));
  F8 u;
#pragma unroll
  for(int i=0;i<8;i++) u.v[i] = fmaf(t.v[i]*inv, wv.v[i], bv.v[i]);
  float s2u = wredsum(ssq8(u));
  float nu  = sqrtf(fmaxf(s2u, EPS2f));
  float se  = tanhf(nu)/nu;
#pragma unroll
  for(int i=0;i<8;i++) u.v[i] *= se;     // p = expmap0(u)
  float s2p = wredsum(ssq8(u));
  float npn = sqrtf(fmaxf(s2p, EPS2f));
  float nc2 = fminf(fmaxf(npn, EPSf), MAXNf);
  float al  = atanhf(nc2)/nc2;
#pragma unroll
  for(int i=0;i<8;i++) u.v[i] *= al;     // t = logmap0(p)
  st8(tout + o, u);
}

// t = logmap0(p)  (D=512 rows)
__global__ void k_logmap(const float* __restrict__ in, float* __restrict__ out){
  const int r = blockIdx.x, lane = threadIdx.x;
  const size_t o = (size_t)r*D_ + (lane<<3);
  F8 x = ld8(in + o);
  float s2 = wredsum(ssq8(x));
  float n  = sqrtf(fmaxf(s2, EPS2f));
  float nc = fminf(fmaxf(n, EPSf), MAXNf);
  float a  = atanhf(nc)/nc;
#pragma unroll
  for(int i=0;i<8;i++) x.v[i] *= a;
  st8(out + o, x);
}

// sum partials -> expmap0 -> logmap0 -> *betaS -> per-head expmap0 -> head layout
// mode 0: Q (vals only)  1: K (vals + k2)  2: V (lam*v vals + lam-1)
__global__ void k_split(const float* __restrict__ up, float* __restrict__ vout,
                        float* __restrict__ aux, int mode, float betaS){
  const int r = blockIdx.x, lane = threadIdx.x;
  const int b = r / S_, s = r % S_;
  const size_t o = (size_t)r*D_ + (lane<<3);
  F8 u = ld8(up + o);
  for(int ks=1; ks<KS_; ks++){
    F8 t = ld8(up + (size_t)ks*N_*D_ + o);
#pragma unroll
    for(int i=0;i<8;i++) u.v[i] += t.v[i];
  }
  float s2u = wredsum(ssq8(u));
  float n   = sqrtf(fmaxf(s2u, EPS2f));
  float se  = tanhf(n)/n;
#pragma unroll
  for(int i=0;i<8;i++) u.v[i] *= se;     // p = expmap0(u)
  float s2p = wredsum(ssq8(u));
  float np  = sqrtf(fmaxf(s2p, EPS2f));
  float nc  = fminf(fmaxf(np, EPSf), MAXNf);
  float al  = atanhf(nc)/nc * betaS;
#pragma unroll
  for(int i=0;i<8;i++) u.v[i] *= al;     // t = logmap0(p)*betaS
  float s2h = g8sum(ssq8(u));            // per-head (64-dim) norm
  float nh  = sqrtf(fmaxf(s2h, EPS2f));
  float sh  = tanhf(nh)/nh;
#pragma unroll
  for(int i=0;i<8;i++) u.v[i] *= sh;     // head expmap0
  const int head = lane>>3, d0 = (lane&7)<<3;
  const size_t ho = ((size_t)(b*H_+head)*S_ + s)*HD_ + d0;
  if (mode == 2){
    float v2  = g8sum(ssq8(u));
    float lam = 2.f/fmaxf(1.f - v2, EPSf);
    F8 lv;
#pragma unroll
    for(int i=0;i<8;i++) lv.v[i] = u.v[i]*lam;
    st8(vout + ho, lv);
    if((lane&7)==0) aux[(size_t)(b*H_+head)*S_ + s] = lam - 1.f;
  } else {
    st8(vout + ho, u);
    if(mode == 1){
      float k2 = g8sum(ssq8(u));
      if((lane&7)==0) aux[(size_t)(b*H_+head)*S_ + s] = k2;
    }
  }
}

// fused causal hyperbolic attention, key-split partials.
// softmax normalization cancels in num/den; scores <= 0 so exp(s) is safe un-shifted.
// grid: 16 bh * 16 qtiles * 4 ksplits = 1024 blocks of 1 wave.
__global__ __launch_bounds__(64) void k_attn(
    const float* __restrict__ qh, const float* __restrict__ kh,
    const float* __restrict__ k2a, const float* __restrict__ lamv,
    const float* __restrict__ lm1, const float* __restrict__ taup,
    const float* __restrict__ gamp, float* __restrict__ nump,
    float* __restrict__ denp){
  const int bid = blockIdx.x;
  const int bh  = bid >> 6;
  const int qt  = (bid & 63) >> 2;
  const int ks  = bid & 3;
  if ((ks<<2) > qt) return;              // key quarter entirely above the diagonal
  const int lane = threadIdx.x;
  const int i    = (qt<<6) + lane;       // this thread's query row
  const float tau = *taup, gam = *gamp;
  __shared__ float4 Kt[64][16];
  __shared__ float4 Vt[64][16];
  __shared__ float  k2s[64];
  __shared__ float  l1s[64];
  const float4* qp = (const float4*)(qh + ((size_t)bh*S_ + i)*HD_);
  float4 q[16];
#pragma unroll
  for(int c=0;c<16;c++) q[c] = qp[c];
  float q2 = 0.f;
#pragma unroll
  for(int c=0;c<16;c++){
    q2 = fmaf(q[c].x,q[c].x,q2); q2 = fmaf(q[c].y,q[c].y,q2);
    q2 = fmaf(q[c].z,q[c].z,q2); q2 = fmaf(q[c].w,q[c].w,q2);
  }
  const float omq = 1.f - q2;
  float4 acc[16];
#pragma unroll
  for(int c=0;c<16;c++) acc[c] = make_float4(0.f,0.f,0.f,0.f);
  float dacc = 0.f;
  for(int kt=0; kt<4; kt++){
    const int j0 = (ks<<8) + (kt<<6);
    if (j0 > (qt<<6)) break;             // both multiples of 64
    __syncthreads();
    const float4* kp = (const float4*)(kh   + ((size_t)bh*S_ + j0)*HD_);
    const float4* vp = (const float4*)(lamv + ((size_t)bh*S_ + j0)*HD_);
    float4* kf = &Kt[0][0];
    float4* vf = &Vt[0][0];
#pragma unroll
    for(int it=0; it<16; it++){
      const int f = (it<<6) + lane;
      kf[f] = kp[f];
      vf[f] = vp[f];
    }
    k2s[lane] = k2a[(size_t)bh*S_ + j0 + lane];
    l1s[lane] = lm1[(size_t)bh*S_ + j0 + lane];
    __syncthreads();
    const int jmax = i - j0;             // >= 0 whenever tile is processed
    for(int j=0;j<64;j++){
      float dot = 0.f;
#pragma unroll
      for(int c=0;c<16;c++){
        const float4 k4 = Kt[j][c];      // wave-uniform address -> LDS broadcast
        dot = fmaf(q[c].x,k4.x,dot); dot = fmaf(q[c].y,k4.y,dot);
        dot = fmaf(q[c].z,k4.z,dot); dot = fmaf(q[c].w,k4.w,dot);
      }
      const float k2v  = k2s[j];
      const float d2   = fmaxf(q2 + k2v - 2.f*dot, 0.f);
      const float dn   = fmaxf(omq*(1.f-k2v), EPSf);
      const float z    = fmaxf(1.f + 2.f*d2/dn, 1.f + 1e-7f);
      const float dist = __logf(z + __fsqrt_rn(fmaf(z,z,-1.f)));   // arccosh
      const float sc   = fmaf(-tau, dist, -gam);
      const float wgt  = (j <= jmax) ? __expf(sc) : 0.f;
      dacc = fmaf(wgt, l1s[j], dacc);
#pragma unroll
      for(int c=0;c<16;c++){
        const float4 v4 = Vt[j][c];
        acc[c].x = fmaf(wgt, v4.x, acc[c].x);
        acc[c].y = fmaf(wgt, v4.y, acc[c].y);
        acc[c].z = fmaf(wgt, v4.z, acc[c].z);
        acc[c].w = fmaf(wgt, v4.w, acc[c].w);
      }
    }
  }
  float4* np = (float4*)(nump + ((size_t)ks*BHS_ + (size_t)bh*S_ + i)*HD_);
#pragma unroll
  for(int c=0;c<16;c++) np[c] = acc[c];
  denp[(size_t)ks*BHS_ + (size_t)bh*S_ + i] = dacc;
}

// combine key-split partials -> midpoint -> 0.5-scalar-mul -> project -> beta-concat -> ball point row
__global__ void k_combine(const float* __restrict__ nump, const float* __restrict__ denp,
                          float* __restrict__ pout, float betaC){
  const int r = blockIdx.x, lane = threadIdx.x;
  const int b = r / S_, s = r % S_;
  const int nks  = (s >> 8) + 1;          // valid key-splits for row s
  const int head = lane >> 3;
  const int d0   = (lane & 7) << 3;
  const size_t hrow = (size_t)(b*H_ + head)*S_ + s;
  F8 num;
#pragma unroll
  for(int i=0;i<8;i++) num.v[i]=0.f;
  float den = 0.f;
  for(int ks=0; ks<nks; ks++){
    F8 t = ld8(nump + ((size_t)ks*BHS_ + hrow)*HD_ + d0);
#pragma unroll
    for(int i=0;i<8;i++) num.v[i] += t.v[i];
    den += denp[(size_t)ks*BHS_ + hrow];
  }
  den = fmaxf(den, EPSf);
  F8 y;
#pragma unroll
  for(int i=0;i<8;i++) y.v[i] = num.v[i]/den;          // mid
  float s2 = g8sum(ssq8(y));
  float n  = fminf(fmaxf(sqrtf(fmaxf(s2,EPS2f)), EPSf), MAXNf);
  float ms = tanhf(0.5f*atanhf(n))/n;                  // mobius_scalar_mul(0.5)
#pragma unroll
  for(int i=0;i<8;i++) y.v[i] *= ms;
  float s2y = g8sum(ssq8(y));
  float ny  = sqrtf(fmaxf(s2y, EPS2f));
  float pf  = fminf(1.f, MAXNf/ny);                    // project
#pragma unroll
  for(int i=0;i<8;i++) y.v[i] *= pf;
  float s2c = g8sum(ssq8(y));
  float np2 = sqrtf(fmaxf(s2c, EPS2f));
  float ncc = fminf(fmaxf(np2, EPSf), MAXNf);
  float al  = atanhf(ncc)/ncc * betaC;                 // per-head logmap * beta-concat
#pragma unroll
  for(int i=0;i<8;i++) y.v[i] *= al;
  float s2t = wredsum(ssq8(y));                        // expmap over full 512 row
  float nt  = sqrtf(fmaxf(s2t, EPS2f));
  float se  = tanhf(nt)/nt;
#pragma unroll
  for(int i=0;i<8;i++) y.v[i] *= se;
  st8(pout + (size_t)r*D_ + head*HD_ + d0, y);
}

// FFN middle: u1 -> expmap -> logmap -> relu -> expmap -> logmap -> t2  (FF=2048 rows)
__global__ void k_ffn_mid(const float* __restrict__ u, float* __restrict__ tout){
  const int r = blockIdx.x, lane = threadIdx.x;
  const float* bp = u + (size_t)r*FF_ + (lane<<5);
  float4 x[8];
#pragma unroll
  for(int c=0;c<8;c++) x[c] = *(const float4*)(bp + (c<<2));
  float ls;
#define SSQ8x4(out) { out=0.f; _Pragma("unroll") for(int c=0;c<8;c++){ out=fmaf(x[c].x,x[c].x,out); out=fmaf(x[c].y,x[c].y,out); out=fmaf(x[c].z,x[c].z,out); out=fmaf(x[c].w,x[c].w,out);} }
#define SCALE8x4(a) { _Pragma("unroll") for(int c=0;c<8;c++){ x[c].x*=(a); x[c].y*=(a); x[c].z*=(a); x[c].w*=(a);} }
  SSQ8x4(ls);
  float s2 = wredsum(ls);
  float n  = sqrtf(fmaxf(s2, EPS2f));
  SCALE8x4(tanhf(n)/n);                                 // p1 = expmap0(u1)
  SSQ8x4(ls); s2 = wredsum(ls);
  n = sqrtf(fmaxf(s2, EPS2f));
  float nc = fminf(fmaxf(n, EPSf), MAXNf);
  SCALE8x4(atanhf(nc)/nc);                              // t1 = logmap0(p1)
#pragma unroll
  for(int c=0;c<8;c++){
    x[c].x=fmaxf(x[c].x,0.f); x[c].y=fmaxf(x[c].y,0.f);
    x[c].z=fmaxf(x[c].z,0.f); x[c].w=fmaxf(x[c].w,0.f); // relu
  }
  SSQ8x4(ls); s2 = wredsum(ls);
  n = sqrtf(fmaxf(s2, EPS2f));
  SCALE8x4(tanhf(n)/n);                                 // p2 = expmap0(relu)
  SSQ8x4(ls); s2 = wredsum(ls);
  n = sqrtf(fmaxf(s2, EPS2f));
  nc = fminf(fmaxf(n, EPSf), MAXNf);
  SCALE8x4(atanhf(nc)/nc);                              // t2 = logmap0(p2)
  float* op = tout + (size_t)r*FF_ + (lane<<5);
#pragma unroll
  for(int c=0;c<8;c++) *(float4*)(op + (c<<2)) = x[c];
#undef SSQ8x4
#undef SCALE8x4
}

// final: sum partials -> expmap0 -> d_out
__global__ void k_final(const float* __restrict__ up, float* __restrict__ out){
  const int r = blockIdx.x, lane = threadIdx.x;
  const size_t o = (size_t)r*D_ + (lane<<3);
  F8 u = ld8(up + o);
  for(int ks=1; ks<KS_; ks++){
    F8 t = ld8(up + (size_t)ks*N_*D_ + o);
#pragma unroll
    for(int i=0;i<8;i++) u.v[i] += t.v[i];
  }
  float s2 = wredsum(ssq8(u));
  float n  = sqrtf(fmaxf(s2, EPS2f));
  float se = tanhf(n)/n;
#pragma unroll
  for(int i=0;i<8;i++) u.v[i] *= se;
  st8(out + o, u);
}

// C[ks][n][m] (+bias at ks==0) = A[n][k] * W[m][k]^T over k-range of this split.
// 64 threads, 64x64 tile, 8x8 microtile, K-step 32, k-major LDS (stride 68: 16B-aligned, odd/32 banks).
#define GST 68
__global__ __launch_bounds__(64) void k_gemm(
    const float* __restrict__ A, const float* __restrict__ W,
    const float* __restrict__ bias, float* __restrict__ C,
    int K, int M, int kslen){
  __shared__ float As[32*GST];
  __shared__ float Ws[32*GST];
  const int lane = threadIdx.x;
  const int m0 = blockIdx.x << 6;
  const int n0 = blockIdx.y << 6;
  const int ks = blockIdx.z;
  const int tx = lane & 7, ty = lane >> 3;
  float acc[8][8];
#pragma unroll
  for(int i=0;i<8;i++)
#pragma unroll
    for(int j=0;j<8;j++) acc[i][j]=0.f;
  const int kend = (ks+1)*kslen;
  for(int k0 = ks*kslen; k0 < kend; k0 += 32){
    __syncthreads();
#pragma unroll
    for(int it=0; it<8; it++){
      const int f  = (it<<6) + lane;
      const int rr = f >> 3;
      const int c4 = (f & 7) << 2;
      const float4 av = *(const float4*)(A + (size_t)(n0+rr)*K + k0 + c4);
      const float4 wv = *(const float4*)(W + (size_t)(m0+rr)*K + k0 + c4);
      As[(c4+0)*GST + rr] = av.x; As[(c4+1)*GST + rr] = av.y;
      As[(c4+2)*GST + rr] = av.z; As[(c4+3)*GST + rr] = av.w;
      Ws[(c4+0)*GST + rr] = wv.x; Ws[(c4+1)*GST + rr] = wv.y;
      Ws[(c4+2)*GST + rr] = wv.z; Ws[(c4+3)*GST + rr] = wv.w;
    }
    __syncthreads();
#pragma unroll 8
    for(int kk=0; kk<32; kk++){
      const float* ar = &As[kk*GST + (ty<<3)];
      const float* wr = &Ws[kk*GST + (tx<<3)];
      const float4 a0 = *(const float4*)ar;
      const float4 a1 = *(const float4*)(ar+4);
      const float4 w0 = *(const float4*)wr;
      const float4 w1 = *(const float4*)(wr+4);
      const float a8[8] = {a0.x,a0.y,a0.z,a0.w,a1.x,a1.y,a1.z,a1.w};
      const float w8[8] = {w0.x,w0.y,w0.z,w0.w,w1.x,w1.y,w1.z,w1.w};
#pragma unroll
      for(int i=0;i<8;i++)
#pragma unroll
        for(int j=0;j<8;j++)
          acc[i][j] = fmaf(a8[i], w8[j], acc[i][j]);
    }
  }
  const size_t cbase = (size_t)ks*N_*M;
#pragma unroll
  for(int i=0;i<8;i++){
    const int rr = n0 + (ty<<3) + i;
    float o8[8];
#pragma unroll
    for(int j=0;j<8;j++) o8[j] = acc[i][j];
    if (ks == 0){
#pragma unroll
      for(int j=0;j<8;j++) o8[j] += bias[m0 + (tx<<3) + j];
    }
    float* cp = C + cbase + (size_t)rr*M + m0 + (tx<<3);
    *(float4*)cp     = make_float4(o8[0],o8[1],o8[2],o8[3]);
    *(float4*)(cp+4) = make_float4(o8[4],o8[5],o8[6],o8[7]);
  }
}

// ---------------- host ----------------
extern "C" void kernel_launch(void* const* d_in, const int* in_sizes, int n_in,
                              void* d_out, int out_size, void* d_ws, size_t ws_size,
                              hipStream_t stream){
  const float* x_in = (const float*)d_in[0];
  const float* pos  = (const float*)d_in[1];
  const float* ln1w = (const float*)d_in[2];
  const float* ln1b = (const float*)d_in[3];
  const float* ln2w = (const float*)d_in[4];
  const float* ln2b = (const float*)d_in[5];
  const float* Wq   = (const float*)d_in[6];
  const float* bq   = (const float*)d_in[7];
  const float* Wk   = (const float*)d_in[8];
  const float* bk   = (const float*)d_in[9];
  const float* Wv   = (const float*)d_in[10];
  const float* bv   = (const float*)d_in[11];
  const float* Wo   = (const float*)d_in[12];
  const float* bo   = (const float*)d_in[13];
  const float* W1   = (const float*)d_in[14];
  const float* b1   = (const float*)d_in[15];
  const float* W2   = (const float*)d_in[16];
  const float* b2   = (const float*)d_in[17];
  const float* tau  = (const float*)d_in[18];
  const float* gam  = (const float*)d_in[19];
  const float* Wout = (const float*)d_in[20];
  const float* bout = (const float*)d_in[21];

  float* ws = (float*)d_ws;
  float* xb  = ws;                              // [N,D]           x (ball), updated per layer
  float* tb  = xb  + (size_t)N_*D_;             // [N,FF] max      tangent rows (stride D or FF)
  float* ub  = tb  + (size_t)N_*FF_;            // [KS,N,512] or [N,FF]  gemm out; aliased as attn num partials
  float* qhb = ub  + (size_t)N_*FF_;            // [B,H,S,HD]      Q heads; aliased as p_att after attention
  float* khb = qhb + (size_t)N_*D_;             // [B,H,S,HD]      K heads
  float* lvb = khb + (size_t)N_*D_;             // [B,H,S,HD]      lam*v
  float* k2b = lvb + (size_t)N_*D_;             // [B,H,S]         |k|^2
  float* l1b = k2b + (size_t)BHS_;              // [B,H,S]         lam-1
  float* dnb = l1b + (size_t)BHS_;              // [KS,B,H,S]      den partials
  float* nump = ub;                             // alias: KS_*N_*D_ == N_*FF_
  float* patt = qhb;                            // alias: Q heads dead once attention done

  // beta-split/concat scalars (reference computes in double then applies as f32)
  const double bd  = exp(lgamma(D_/2.0)  + lgamma(0.5) - lgamma(D_/2.0  + 0.5));
  const double bhd = exp(lgamma(HD_/2.0) + lgamma(0.5) - lgamma(HD_/2.0 + 0.5));
  const float betaS = (float)(bhd/bd);
  const float betaC = (float)(bd/bhd);

  const dim3 g512(D_/64,  N_/64, KS_);   // (8,32,4)  M=512 GEMMs, split-K
  const dim3 gff1(FF_/64, N_/64, 1);     // (32,32,1) M=2048 GEMM, no split
  const dim3 gff2(D_/64,  N_/64, KS_);   // (8,32,4)  M=512, K=2048

  k_mobius_pos<<<N_,64,0,stream>>>(x_in, pos, xb);
  for(int l=0; l<L_; l++){
    k_pln_tan<<<N_,64,0,stream>>>(xb, ln1w + l*D_, ln1b + l*D_, tb);
    k_gemm<<<g512,64,0,stream>>>(tb, Wq + (size_t)l*D_*D_, bq + l*D_, ub, D_, D_, D_/KS_);
    k_split<<<N_,64,0,stream>>>(ub, qhb, k2b /*unused*/, 0, betaS);
    k_gemm<<<g512,64,0,stream>>>(tb, Wk + (size_t)l*D_*D_, bk + l*D_, ub, D_, D_, D_/KS_);
    k_split<<<N_,64,0,stream>>>(ub, khb, k2b, 1, betaS);
    k_gemm<<<g512,64,0,stream>>>(tb, Wv + (size_t)l*D_*D_, bv + l*D_, ub, D_, D_, D_/KS_);
    k_split<<<N_,64,0,stream>>>(ub, lvb, l1b, 2, betaS);
    k_attn<<<1024,64,0,stream>>>(qhb, khb, k2b, lvb, l1b, tau + l, gam + l, nump, dnb);
    k_combine<<<N_,64,0,stream>>>(nump, dnb, patt, betaC);
    k_logmap<<<N_,64,0,stream>>>(patt, tb);
    k_gemm<<<g512,64,0,stream>>>(tb, Wo + (size_t)l*D_*D_, bo + l*D_, ub, D_, D_, D_/KS_);
    k_mobius_epi<<<N_,64,0,stream>>>(ub, xb);
    k_pln_tan<<<N_,64,0,stream>>>(xb, ln2w + l*D_, ln2b + l*D_, tb);
    k_gemm<<<gff1,64,0,stream>>>(tb, W1 + (size_t)l*FF_*D_, b1 + l*FF_, ub, D_, FF_, D_);
    k_ffn_mid<<<N_,64,0,stream>>>(ub, tb);
    k_gemm<<<gff2,64,0,stream>>>(tb, W2 + (size_t)l*D_*FF_, b2 + l*D_, ub, FF_, D_, FF_/KS_);
    k_mobius_epi<<<N_,64,0,stream>>>(ub, xb);
  }
  k_logmap<<<N_,64,0,stream>>>(xb, tb);
  k_gemm<<<g512,64,0,stream>>>(tb, Wout, bout, ub, D_, D_, D_/KS_);
  k_final<<<N_,64,0,stream>>>(ub, (float*)d_out);
}

// Round 2
// 2247.764 us; speedup vs baseline: 1.3618x; 1.3618x over previous
//
#include <hip/hip_runtime.h>
#include <cmath>

// Poincare-ball causal transformer forward, fp32, MI355X.
#define B_ 2
#define S_ 1024
#define D_ 512
#define H_ 8
#define HD_ 64
#define FF_ 2048
#define L_ 4
#define N_ (B_*S_)          // 2048 token rows
#define BHS_ (B_*H_*S_)     // 16384 head rows
#define EPSf 1e-7f
#define EPS2f 1e-14f
#define MAXNf 0.999f
#define KS_ 4               // split-K factor for M=512 GEMMs / attention key splits

// ---------------- small helpers ----------------
struct F8 { float v[8]; };

__device__ __forceinline__ F8 ld8(const float* __restrict__ p){
  F8 r; const float4 a = *(const float4*)p; const float4 b = *(const float4*)(p+4);
  r.v[0]=a.x; r.v[1]=a.y; r.v[2]=a.z; r.v[3]=a.w;
  r.v[4]=b.x; r.v[5]=b.y; r.v[6]=b.z; r.v[7]=b.w;
  return r;
}
__device__ __forceinline__ void st8(float* __restrict__ p, const F8& r){
  *(float4*)p     = make_float4(r.v[0],r.v[1],r.v[2],r.v[3]);
  *(float4*)(p+4) = make_float4(r.v[4],r.v[5],r.v[6],r.v[7]);
}
__device__ __forceinline__ float ssq8(const F8& r){
  float s=0.f;
#pragma unroll
  for(int i=0;i<8;i++) s = fmaf(r.v[i], r.v[i], s);
  return s;
}
__device__ __forceinline__ float sum8(const F8& r){
  float s=0.f;
#pragma unroll
  for(int i=0;i<8;i++) s += r.v[i];
  return s;
}
__device__ __forceinline__ float wredsum(float v){
#pragma unroll
  for(int o=1;o<64;o<<=1) v += __shfl_xor(v,o,64);
  return v;
}
__device__ __forceinline__ float g8sum(float v){
#pragma unroll
  for(int o=1;o<8;o<<=1) v += __shfl_xor(v,o,64);
  return v;
}

__device__ __forceinline__ F8 mobius_add8(const F8& x, const F8& y){
  float x2 = wredsum(ssq8(x));
  float y2 = wredsum(ssq8(y));
  float d = 0.f;
#pragma unroll
  for(int i=0;i<8;i++) d = fmaf(x.v[i], y.v[i], d);
  float xy = wredsum(d);
  float cx  = 1.f + 2.f*xy + y2;
  float cy  = 1.f - x2;
  float den = fmaxf(1.f + 2.f*xy + x2*y2, EPSf);
  F8 z;
#pragma unroll
  for(int i=0;i<8;i++) z.v[i] = (cx*x.v[i] + cy*y.v[i]) / den;
  float s2 = wredsum(ssq8(z));
  float n  = sqrtf(fmaxf(s2, EPS2f));
  float pr = fminf(1.f, MAXNf/n);
#pragma unroll
  for(int i=0;i<8;i++) z.v[i] *= pr;
  return z;
}

// ---------------- kernels ----------------

__global__ void k_mobius_pos(const float* __restrict__ xin, const float* __restrict__ pos,
                             float* __restrict__ xout){
  const int r = blockIdx.x, lane = threadIdx.x;
  const int s = r % S_;
  const size_t o = (size_t)r*D_ + (lane<<3);
  F8 x = ld8(xin + o);
  F8 y = ld8(pos + (size_t)s*D_ + (lane<<3));
  F8 z = mobius_add8(x, y);
  st8(xout + o, z);
}

__global__ void k_mobius_epi(const float* __restrict__ up, float* __restrict__ x){
  const int r = blockIdx.x, lane = threadIdx.x;
  const size_t o = (size_t)r*D_ + (lane<<3);
  F8 u = ld8(up + o);
  for(int ks=1; ks<KS_; ks++){
    F8 t = ld8(up + (size_t)ks*N_*D_ + o);
#pragma unroll
    for(int i=0;i<8;i++) u.v[i] += t.v[i];
  }
  float s2 = wredsum(ssq8(u));
  float n  = sqrtf(fmaxf(s2, EPS2f));
  float se = tanhf(n)/n;
#pragma unroll
  for(int i=0;i<8;i++) u.v[i] *= se;
  F8 xv = ld8(x + o);
  F8 z = mobius_add8(xv, u);
  st8(x + o, z);
}

__global__ void k_pln_tan(const float* __restrict__ xin, const float* __restrict__ w,
                          const float* __restrict__ b, float* __restrict__ tout){
  const int r = blockIdx.x, lane = threadIdx.x;
  const size_t o = (size_t)r*D_ + (lane<<3);
  F8 x = ld8(xin + o);
  float s2 = wredsum(ssq8(x));
  float n  = sqrtf(fmaxf(s2, EPS2f));
  float nc = fminf(fmaxf(n, EPSf), MAXNf);
  float a  = atanhf(nc)/nc;
  F8 t;
#pragma unroll
  for(int i=0;i<8;i++) t.v[i] = x.v[i]*a;
  float mu = wredsum(sum8(t)) * (1.f/(float)D_);
#pragma unroll
  for(int i=0;i<8;i++) t.v[i] -= mu;
  float var = wredsum(ssq8(t)) * (1.f/(float)D_);
  float inv = 1.f/sqrtf(var + 1e-5f);
  F8 wv = ld8(w + (lane<<3));
  F8 bv = ld8(b + (lane<<3));
  F8 u;
#pragma unroll
  for(int i=0;i<8;i++) u.v[i] = fmaf(t.v[i]*inv, wv.v[i], bv.v[i]);
  float s2u = wredsum(ssq8(u));
  float nu  = sqrtf(fmaxf(s2u, EPS2f));
  float se  = tanhf(nu)/nu;
#pragma unroll
  for(int i=0;i<8;i++) u.v[i] *= se;
  float s2p = wredsum(ssq8(u));
  float npn = sqrtf(fmaxf(s2p, EPS2f));
  float nc2 = fminf(fmaxf(npn, EPSf), MAXNf);
  float al  = atanhf(nc2)/nc2;
#pragma unroll
  for(int i=0;i<8;i++) u.v[i] *= al;
  st8(tout + o, u);
}

__global__ void k_logmap(const float* __restrict__ in, float* __restrict__ out){
  const int r = blockIdx.x, lane = threadIdx.x;
  const size_t o = (size_t)r*D_ + (lane<<3);
  F8 x = ld8(in + o);
  float s2 = wredsum(ssq8(x));
  float n  = sqrtf(fmaxf(s2, EPS2f));
  float nc = fminf(fmaxf(n, EPSf), MAXNf);
  float a  = atanhf(nc)/nc;
#pragma unroll
  for(int i=0;i<8;i++) x.v[i] *= a;
  st8(out + o, x);
}

// sum partials -> expmap0 -> logmap0 -> *betaS -> per-head expmap0 -> head layout
__global__ void k_split(const float* __restrict__ up, float* __restrict__ vout,
                        float* __restrict__ aux, int mode, float betaS){
  const int r = blockIdx.x, lane = threadIdx.x;
  const int b = r / S_, s = r % S_;
  const size_t o = (size_t)r*D_ + (lane<<3);
  F8 u = ld8(up + o);
  for(int ks=1; ks<KS_; ks++){
    F8 t = ld8(up + (size_t)ks*N_*D_ + o);
#pragma unroll
    for(int i=0;i<8;i++) u.v[i] += t.v[i];
  }
  float s2u = wredsum(ssq8(u));
  float n   = sqrtf(fmaxf(s2u, EPS2f));
  float se  = tanhf(n)/n;
#pragma unroll
  for(int i=0;i<8;i++) u.v[i] *= se;
  float s2p = wredsum(ssq8(u));
  float np  = sqrtf(fmaxf(s2p, EPS2f));
  float nc  = fminf(fmaxf(np, EPSf), MAXNf);
  float al  = atanhf(nc)/nc * betaS;
#pragma unroll
  for(int i=0;i<8;i++) u.v[i] *= al;
  float s2h = g8sum(ssq8(u));
  float nh  = sqrtf(fmaxf(s2h, EPS2f));
  float sh  = tanhf(nh)/nh;
#pragma unroll
  for(int i=0;i<8;i++) u.v[i] *= sh;
  const int head = lane>>3, d0 = (lane&7)<<3;
  const size_t ho = ((size_t)(b*H_+head)*S_ + s)*HD_ + d0;
  if (mode == 2){
    float v2  = g8sum(ssq8(u));
    float lam = 2.f/fmaxf(1.f - v2, EPSf);
    F8 lv;
#pragma unroll
    for(int i=0;i<8;i++) lv.v[i] = u.v[i]*lam;
    st8(vout + ho, lv);
    if((lane&7)==0) aux[(size_t)(b*H_+head)*S_ + s] = lam - 1.f;
  } else {
    st8(vout + ho, u);
    if(mode == 1){
      float k2 = g8sum(ssq8(u));
      if((lane&7)==0) aux[(size_t)(b*H_+head)*S_ + s] = k2;
    }
  }
}

// fused causal hyperbolic attention, key-split partials.
// 4-wave blocks: waves cooperatively stage each 64x64 K/V tile; wave w computes
// a 16-key strip for all 64 queries; tree-combine through LDS at block end.
// Softmax normalization cancels in num/den; scores <= 0 so exp is safe un-shifted.
#define AST 68   // padded row stride (floats) for LDS tiles (17 float4, odd banks)
__global__ __launch_bounds__(256) void k_attn(
    const float* __restrict__ qh, const float* __restrict__ kh,
    const float* __restrict__ k2a, const float* __restrict__ lamv,
    const float* __restrict__ lm1, const float* __restrict__ taup,
    const float* __restrict__ gamp, float* __restrict__ nump,
    float* __restrict__ denp){
  const int bid = blockIdx.x;
  const int bh  = bid >> 6;
  const int qt  = (bid & 63) >> 2;
  const int ks  = bid & 3;
  if ((ks<<2) > qt) return;              // key quarter entirely above the diagonal
  const int tid  = threadIdx.x;
  const int w    = tid >> 6;             // wave id 0..3
  const int lane = tid & 63;
  const int i    = (qt<<6) + lane;       // this thread's query row
  const float tau = *taup, gam = *gamp;
  __shared__ float Ks[64*AST];
  __shared__ float Vs[64*AST];
  __shared__ float k2s[64];
  __shared__ float l1s[64];
  __shared__ float dden[4][64];
  const float4* qp = (const float4*)(qh + ((size_t)bh*S_ + i)*HD_);
  float4 q[16];
#pragma unroll
  for(int c=0;c<16;c++) q[c] = qp[c];
  float q2 = 0.f;
#pragma unroll
  for(int c=0;c<16;c++){
    q2 = fmaf(q[c].x,q[c].x,q2); q2 = fmaf(q[c].y,q[c].y,q2);
    q2 = fmaf(q[c].z,q[c].z,q2); q2 = fmaf(q[c].w,q[c].w,q2);
  }
  const float omq = 1.f - q2;
  float4 acc[16];
#pragma unroll
  for(int c=0;c<16;c++) acc[c] = make_float4(0.f,0.f,0.f,0.f);
  float dacc = 0.f;
  const int jmax = i;                    // causal: key index <= i
  for(int kt=0; kt<4; kt++){
    const int j0 = (ks<<8) + (kt<<6);
    if (j0 > (qt<<6)) break;             // block-uniform
    __syncthreads();
    const float4* kp = (const float4*)(kh   + ((size_t)bh*S_ + j0)*HD_);
    const float4* vp = (const float4*)(lamv + ((size_t)bh*S_ + j0)*HD_);
#pragma unroll
    for(int it=0; it<4; it++){
      const int f   = (it<<8) + tid;     // 0..1023
      const int row = f >> 4, c4 = f & 15;
      ((float4*)(Ks + row*AST))[c4] = kp[f];
      ((float4*)(Vs + row*AST))[c4] = vp[f];
    }
    if (tid < 64)      k2s[tid]     = k2a[(size_t)bh*S_ + j0 + tid];
    else if (tid <128) l1s[tid-64]  = lm1[(size_t)bh*S_ + j0 + tid - 64];
    __syncthreads();
    for(int jj=0; jj<16; jj++){
      const int j = (w<<4) + jj;
      const float4* kr = (const float4*)(Ks + j*AST);
      float dp[4] = {0.f,0.f,0.f,0.f};
#pragma unroll
      for(int c=0;c<16;c++){
        const float4 k4 = kr[c];         // wave-uniform LDS broadcast
        float d = dp[c&3];
        d = fmaf(q[c].x,k4.x,d); d = fmaf(q[c].y,k4.y,d);
        d = fmaf(q[c].z,k4.z,d); d = fmaf(q[c].w,k4.w,d);
        dp[c&3] = d;
      }
      const float dot  = (dp[0]+dp[1]) + (dp[2]+dp[3]);
      const float k2v  = k2s[j];
      const float d2   = fmaxf(q2 + k2v - 2.f*dot, 0.f);
      const float dn   = fmaxf(omq*(1.f-k2v), EPSf);
      const float z    = fmaxf(1.f + 2.f*d2/dn, 1.f + 1e-7f);
      const float dist = __logf(z + __fsqrt_rn(fmaf(z,z,-1.f)));   // arccosh
      const float wgt  = (j0 + j <= jmax) ? __expf(fmaf(-tau, dist, -gam)) : 0.f;
      dacc = fmaf(wgt, l1s[j], dacc);
      const float4* vr = (const float4*)(Vs + j*AST);
#pragma unroll
      for(int c=0;c<16;c++){
        const float4 v4 = vr[c];
        acc[c].x = fmaf(wgt, v4.x, acc[c].x);
        acc[c].y = fmaf(wgt, v4.y, acc[c].y);
        acc[c].z = fmaf(wgt, v4.z, acc[c].z);
        acc[c].w = fmaf(wgt, v4.w, acc[c].w);
      }
    }
  }
  // ---- block tree-combine: wave0 ends with the full tile sum ----
  __syncthreads();
  dden[w][lane] = dacc;
  if (w==1){ float4* p=(float4*)(Ks + lane*AST);
#pragma unroll
    for(int c=0;c<16;c++) p[c]=acc[c]; }
  if (w==3){ float4* p=(float4*)(Vs + lane*AST);
#pragma unroll
    for(int c=0;c<16;c++) p[c]=acc[c]; }
  __syncthreads();
  if (w==0){ const float4* p=(const float4*)(Ks + lane*AST);
#pragma unroll
    for(int c=0;c<16;c++){ float4 t=p[c];
      acc[c].x+=t.x; acc[c].y+=t.y; acc[c].z+=t.z; acc[c].w+=t.w; }
    dacc += dden[1][lane]; }
  if (w==2){ const float4* p=(const float4*)(Vs + lane*AST);
#pragma unroll
    for(int c=0;c<16;c++){ float4 t=p[c];
      acc[c].x+=t.x; acc[c].y+=t.y; acc[c].z+=t.z; acc[c].w+=t.w; }
    dacc += dden[3][lane]; }
  __syncthreads();
  if (w==2){ float4* p=(float4*)(Ks + lane*AST);
#pragma unroll
    for(int c=0;c<16;c++) p[c]=acc[c];
    dden[2][lane] = dacc; }
  __syncthreads();
  if (w==0){
    const float4* p=(const float4*)(Ks + lane*AST);
#pragma unroll
    for(int c=0;c<16;c++){ float4 t=p[c];
      acc[c].x+=t.x; acc[c].y+=t.y; acc[c].z+=t.z; acc[c].w+=t.w; }
    dacc += dden[2][lane];
    float4* np = (float4*)(nump + ((size_t)ks*BHS_ + (size_t)bh*S_ + i)*HD_);
#pragma unroll
    for(int c=0;c<16;c++) np[c] = acc[c];
    denp[(size_t)ks*BHS_ + (size_t)bh*S_ + i] = dacc;
  }
}

// combine key-split partials -> midpoint -> 0.5-scalar-mul -> project -> beta-concat
__global__ void k_combine(const float* __restrict__ nump, const float* __restrict__ denp,
                          float* __restrict__ pout, float betaC){
  const int r = blockIdx.x, lane = threadIdx.x;
  const int b = r / S_, s = r % S_;
  const int nks  = (s >> 8) + 1;
  const int head = lane >> 3;
  const int d0   = (lane & 7) << 3;
  const size_t hrow = (size_t)(b*H_ + head)*S_ + s;
  F8 num;
#pragma unroll
  for(int i=0;i<8;i++) num.v[i]=0.f;
  float den = 0.f;
  for(int ks=0; ks<nks; ks++){
    F8 t = ld8(nump + ((size_t)ks*BHS_ + hrow)*HD_ + d0);
#pragma unroll
    for(int i=0;i<8;i++) num.v[i] += t.v[i];
    den += denp[(size_t)ks*BHS_ + hrow];
  }
  den = fmaxf(den, EPSf);
  F8 y;
#pragma unroll
  for(int i=0;i<8;i++) y.v[i] = num.v[i]/den;
  float s2 = g8sum(ssq8(y));
  float n  = fminf(fmaxf(sqrtf(fmaxf(s2,EPS2f)), EPSf), MAXNf);
  float ms = tanhf(0.5f*atanhf(n))/n;
#pragma unroll
  for(int i=0;i<8;i++) y.v[i] *= ms;
  float s2y = g8sum(ssq8(y));
  float ny  = sqrtf(fmaxf(s2y, EPS2f));
  float pf  = fminf(1.f, MAXNf/ny);
#pragma unroll
  for(int i=0;i<8;i++) y.v[i] *= pf;
  float s2c = g8sum(ssq8(y));
  float np2 = sqrtf(fmaxf(s2c, EPS2f));
  float ncc = fminf(fmaxf(np2, EPSf), MAXNf);
  float al  = atanhf(ncc)/ncc * betaC;
#pragma unroll
  for(int i=0;i<8;i++) y.v[i] *= al;
  float s2t = wredsum(ssq8(y));
  float nt  = sqrtf(fmaxf(s2t, EPS2f));
  float se  = tanhf(nt)/nt;
#pragma unroll
  for(int i=0;i<8;i++) y.v[i] *= se;
  st8(pout + (size_t)r*D_ + head*HD_ + d0, y);
}

__global__ void k_ffn_mid(const float* __restrict__ u, float* __restrict__ tout){
  const int r = blockIdx.x, lane = threadIdx.x;
  const float* bp = u + (size_t)r*FF_ + (lane<<5);
  float4 x[8];
#pragma unroll
  for(int c=0;c<8;c++) x[c] = *(const float4*)(bp + (c<<2));
  float ls;
#define SSQ8x4(out) { out=0.f; _Pragma("unroll") for(int c=0;c<8;c++){ out=fmaf(x[c].x,x[c].x,out); out=fmaf(x[c].y,x[c].y,out); out=fmaf(x[c].z,x[c].z,out); out=fmaf(x[c].w,x[c].w,out);} }
#define SCALE8x4(a) { _Pragma("unroll") for(int c=0;c<8;c++){ x[c].x*=(a); x[c].y*=(a); x[c].z*=(a); x[c].w*=(a);} }
  SSQ8x4(ls);
  float s2 = wredsum(ls);
  float n  = sqrtf(fmaxf(s2, EPS2f));
  SCALE8x4(tanhf(n)/n);
  SSQ8x4(ls); s2 = wredsum(ls);
  n = sqrtf(fmaxf(s2, EPS2f));
  float nc = fminf(fmaxf(n, EPSf), MAXNf);
  SCALE8x4(atanhf(nc)/nc);
#pragma unroll
  for(int c=0;c<8;c++){
    x[c].x=fmaxf(x[c].x,0.f); x[c].y=fmaxf(x[c].y,0.f);
    x[c].z=fmaxf(x[c].z,0.f); x[c].w=fmaxf(x[c].w,0.f);
  }
  SSQ8x4(ls); s2 = wredsum(ls);
  n = sqrtf(fmaxf(s2, EPS2f));
  SCALE8x4(tanhf(n)/n);
  SSQ8x4(ls); s2 = wredsum(ls);
  n = sqrtf(fmaxf(s2, EPS2f));
  nc = fminf(fmaxf(n, EPSf), MAXNf);
  SCALE8x4(atanhf(nc)/nc);
  float* op = tout + (size_t)r*FF_ + (lane<<5);
#pragma unroll
  for(int c=0;c<8;c++) *(float4*)(op + (c<<2)) = x[c];
#undef SSQ8x4
#undef SCALE8x4
}

__global__ void k_final(const float* __restrict__ up, float* __restrict__ out){
  const int r = blockIdx.x, lane = threadIdx.x;
  const size_t o = (size_t)r*D_ + (lane<<3);
  F8 u = ld8(up + o);
  for(int ks=1; ks<KS_; ks++){
    F8 t = ld8(up + (size_t)ks*N_*D_ + o);
#pragma unroll
    for(int i=0;i<8;i++) u.v[i] += t.v[i];
  }
  float s2 = wredsum(ssq8(u));
  float n  = sqrtf(fmaxf(s2, EPS2f));
  float se = tanhf(n)/n;
#pragma unroll
  for(int i=0;i<8;i++) u.v[i] *= se;
  st8(out + o, u);
}

// C[ks][n][m] (+bias at ks==0) = A[n][k] * W[m][k]^T over k-range of this split.
#define GST 68
__global__ __launch_bounds__(64) void k_gemm(
    const float* __restrict__ A, const float* __restrict__ W,
    const float* __restrict__ bias, float* __restrict__ C,
    int K, int M, int kslen){
  __shared__ float As[32*GST];
  __shared__ float Ws[32*GST];
  const int lane = threadIdx.x;
  const int m0 = blockIdx.x << 6;
  const int n0 = blockIdx.y << 6;
  const int ks = blockIdx.z;
  const int tx = lane & 7, ty = lane >> 3;
  float acc[8][8];
#pragma unroll
  for(int i=0;i<8;i++)
#pragma unroll
    for(int j=0;j<8;j++) acc[i][j]=0.f;
  const int kend = (ks+1)*kslen;
  for(int k0 = ks*kslen; k0 < kend; k0 += 32){
    __syncthreads();
#pragma unroll
    for(int it=0; it<8; it++){
      const int f  = (it<<6) + lane;
      const int rr = f >> 3;
      const int c4 = (f & 7) << 2;
      const float4 av = *(const float4*)(A + (size_t)(n0+rr)*K + k0 + c4);
      const float4 wv = *(const float4*)(W + (size_t)(m0+rr)*K + k0 + c4);
      As[(c4+0)*GST + rr] = av.x; As[(c4+1)*GST + rr] = av.y;
      As[(c4+2)*GST + rr] = av.z; As[(c4+3)*GST + rr] = av.w;
      Ws[(c4+0)*GST + rr] = wv.x; Ws[(c4+1)*GST + rr] = wv.y;
      Ws[(c4+2)*GST + rr] = wv.z; Ws[(c4+3)*GST + rr] = wv.w;
    }
    __syncthreads();
#pragma unroll 8
    for(int kk=0; kk<32; kk++){
      const float* ar = &As[kk*GST + (ty<<3)];
      const float* wr = &Ws[kk*GST + (tx<<3)];
      const float4 a0 = *(const float4*)ar;
      const float4 a1 = *(const float4*)(ar+4);
      const float4 w0 = *(const float4*)wr;
      const float4 w1 = *(const float4*)(wr+4);
      const float a8[8] = {a0.x,a0.y,a0.z,a0.w,a1.x,a1.y,a1.z,a1.w};
      const float w8[8] = {w0.x,w0.y,w0.z,w0.w,w1.x,w1.y,w1.z,w1.w};
#pragma unroll
      for(int i=0;i<8;i++)
#pragma unroll
        for(int j=0;j<8;j++)
          acc[i][j] = fmaf(a8[i], w8[j], acc[i][j]);
    }
  }
  const size_t cbase = (size_t)ks*N_*M;
#pragma unroll
  for(int i=0;i<8;i++){
    const int rr = n0 + (ty<<3) + i;
    float o8[8];
#pragma unroll
    for(int j=0;j<8;j++) o8[j] = acc[i][j];
    if (ks == 0){
#pragma unroll
      for(int j=0;j<8;j++) o8[j] += bias[m0 + (tx<<3) + j];
    }
    float* cp = C + cbase + (size_t)rr*M + m0 + (tx<<3);
    *(float4*)cp     = make_float4(o8[0],o8[1],o8[2],o8[3]);
    *(float4*)(cp+4) = make_float4(o8[4],o8[5],o8[6],o8[7]);
  }
}

// ---------------- host ----------------
extern "C" void kernel_launch(void* const* d_in, const int* in_sizes, int n_in,
                              void* d_out, int out_size, void* d_ws, size_t ws_size,
                              hipStream_t stream){
  const float* x_in = (const float*)d_in[0];
  const float* pos  = (const float*)d_in[1];
  const float* ln1w = (const float*)d_in[2];
  const float* ln1b = (const float*)d_in[3];
  const float* ln2w = (const float*)d_in[4];
  const float* ln2b = (const float*)d_in[5];
  const float* Wq   = (const float*)d_in[6];
  const float* bq   = (const float*)d_in[7];
  const float* Wk   = (const float*)d_in[8];
  const float* bk   = (const float*)d_in[9];
  const float* Wv   = (const float*)d_in[10];
  const float* bv   = (const float*)d_in[11];
  const float* Wo   = (const float*)d_in[12];
  const float* bo   = (const float*)d_in[13];
  const float* W1   = (const float*)d_in[14];
  const float* b1   = (const float*)d_in[15];
  const float* W2   = (const float*)d_in[16];
  const float* b2   = (const float*)d_in[17];
  const float* tau  = (const float*)d_in[18];
  const float* gam  = (const float*)d_in[19];
  const float* Wout = (const float*)d_in[20];
  const float* bout = (const float*)d_in[21];

  float* ws = (float*)d_ws;
  float* xb  = ws;                              // [N,D]
  float* tb  = xb  + (size_t)N_*D_;             // [N,FF] max
  float* ub  = tb  + (size_t)N_*FF_;            // [KS,N,512] or [N,FF]; aliased as attn num partials
  float* qhb = ub  + (size_t)N_*FF_;            // [B,H,S,HD]; aliased as p_att after attention
  float* khb = qhb + (size_t)N_*D_;             // [B,H,S,HD]
  float* lvb = khb + (size_t)N_*D_;             // [B,H,S,HD]  lam*v
  float* k2b = lvb + (size_t)N_*D_;             // [B,H,S]     |k|^2
  float* l1b = k2b + (size_t)BHS_;              // [B,H,S]     lam-1
  float* dnb = l1b + (size_t)BHS_;              // [KS,B,H,S]  den partials
  float* nump = ub;
  float* patt = qhb;

  const double bd  = exp(lgamma(D_/2.0)  + lgamma(0.5) - lgamma(D_/2.0  + 0.5));
  const double bhd = exp(lgamma(HD_/2.0) + lgamma(0.5) - lgamma(HD_/2.0 + 0.5));
  const float betaS = (float)(bhd/bd);
  const float betaC = (float)(bd/bhd);

  const dim3 g512(D_/64,  N_/64, KS_);
  const dim3 gff1(FF_/64, N_/64, 1);
  const dim3 gff2(D_/64,  N_/64, KS_);

  k_mobius_pos<<<N_,64,0,stream>>>(x_in, pos, xb);
  for(int l=0; l<L_; l++){
    k_pln_tan<<<N_,64,0,stream>>>(xb, ln1w + l*D_, ln1b + l*D_, tb);
    k_gemm<<<g512,64,0,stream>>>(tb, Wq + (size_t)l*D_*D_, bq + l*D_, ub, D_, D_, D_/KS_);
    k_split<<<N_,64,0,stream>>>(ub, qhb, k2b /*unused*/, 0, betaS);
    k_gemm<<<g512,64,0,stream>>>(tb, Wk + (size_t)l*D_*D_, bk + l*D_, ub, D_, D_, D_/KS_);
    k_split<<<N_,64,0,stream>>>(ub, khb, k2b, 1, betaS);
    k_gemm<<<g512,64,0,stream>>>(tb, Wv + (size_t)l*D_*D_, bv + l*D_, ub, D_, D_, D_/KS_);
    k_split<<<N_,64,0,stream>>>(ub, lvb, l1b, 2, betaS);
    k_attn<<<1024,256,0,stream>>>(qhb, khb, k2b, lvb, l1b, tau + l, gam + l, nump, dnb);
    k_combine<<<N_,64,0,stream>>>(nump, dnb, patt, betaC);
    k_logmap<<<N_,64,0,stream>>>(patt, tb);
    k_gemm<<<g512,64,0,stream>>>(tb, Wo + (size_t)l*D_*D_, bo + l*D_, ub, D_, D_, D_/KS_);
    k_mobius_epi<<<N_,64,0,stream>>>(ub, xb);
    k_pln_tan<<<N_,64,0,stream>>>(xb, ln2w + l*D_, ln2b + l*D_, tb);
    k_gemm<<<gff1,64,0,stream>>>(tb, W1 + (size_t)l*FF_*D_, b1 + l*FF_, ub, D_, FF_, D_);
    k_ffn_mid<<<N_,64,0,stream>>>(ub, tb);
    k_gemm<<<gff2,64,0,stream>>>(tb, W2 + (size_t)l*D_*FF_, b2 + l*D_, ub, FF_, D_, FF_/KS_);
    k_mobius_epi<<<N_,64,0,stream>>>(ub, xb);
  }
  k_logmap<<<N_,64,0,stream>>>(xb, tb);
  k_gemm<<<g512,64,0,stream>>>(tb, Wout, bout, ub, D_, D_, D_/KS_);
  k_final<<<N_,64,0,stream>>>(ub, (float*)d_out);
}

// Round 4
// 1309.822 us; speedup vs baseline: 2.3370x; 1.7161x over previous
//
#include <hip/hip_runtime.h>
#include <cmath>

// Poincare-ball causal transformer forward, MI355X.
// GEMMs via bf16 hi/lo 3-product MFMA (fp32-faithful); everything else fp32.
#define B_ 2
#define S_ 1024
#define D_ 512
#define H_ 8
#define HD_ 64
#define FF_ 2048
#define L_ 4
#define N_ (B_*S_)          // 2048 token rows
#define BHS_ (B_*H_*S_)     // 16384 head rows
#define EPSf 1e-7f
#define EPS2f 1e-14f
#define MAXNf 0.999f
#define KSG_ 8              // split-K partials for M=512 MFMA GEMMs
#define KSF_ 2              // split-K partials for FF1 (M=2048)
#define KSA_ 4              // attention key splits

typedef unsigned short u16;
typedef __attribute__((ext_vector_type(8))) short s16x8;           // 8 bf16 (MFMA A/B frag)
typedef __attribute__((ext_vector_type(8))) unsigned short u16x8;
typedef __attribute__((ext_vector_type(4))) float f32x4;           // MFMA C/D frag

// ---------------- small helpers ----------------
struct F8 { float v[8]; };

__device__ __forceinline__ F8 ld8(const float* __restrict__ p){
  F8 r; const float4 a = *(const float4*)p; const float4 b = *(const float4*)(p+4);
  r.v[0]=a.x; r.v[1]=a.y; r.v[2]=a.z; r.v[3]=a.w;
  r.v[4]=b.x; r.v[5]=b.y; r.v[6]=b.z; r.v[7]=b.w;
  return r;
}
__device__ __forceinline__ void st8(float* __restrict__ p, const F8& r){
  *(float4*)p     = make_float4(r.v[0],r.v[1],r.v[2],r.v[3]);
  *(float4*)(p+4) = make_float4(r.v[4],r.v[5],r.v[6],r.v[7]);
}
__device__ __forceinline__ float ssq8(const F8& r){
  float s=0.f;
#pragma unroll
  for(int i=0;i<8;i++) s = fmaf(r.v[i], r.v[i], s);
  return s;
}
__device__ __forceinline__ float sum8(const F8& r){
  float s=0.f;
#pragma unroll
  for(int i=0;i<8;i++) s += r.v[i];
  return s;
}
__device__ __forceinline__ float wredsum(float v){
#pragma unroll
  for(int o=1;o<64;o<<=1) v += __shfl_xor(v,o,64);
  return v;
}
__device__ __forceinline__ float g8sum(float v){
#pragma unroll
  for(int o=1;o<8;o<<=1) v += __shfl_xor(v,o,64);
  return v;
}

// bf16 hi/lo split: hi = RN(x), lo = RN(x - hi); x-hi is exact in fp32.
__device__ __forceinline__ void bfsplit(float x, u16& h, u16& l){
  unsigned u = __float_as_uint(x);
  h = (u16)((u + 0x7FFFu + ((u>>16)&1u))>>16);
  float back = __uint_as_float(((unsigned)h)<<16);
  float r = x - back;
  unsigned u2 = __float_as_uint(r);
  l = (u16)((u2 + 0x7FFFu + ((u2>>16)&1u))>>16);
}
__device__ __forceinline__ void st8bf(u16* __restrict__ hp, u16* __restrict__ lp, const F8& r){
  u16x8 h, l;
#pragma unroll
  for(int i=0;i<8;i++){ u16 hh,ll; bfsplit(r.v[i],hh,ll); h[i]=hh; l[i]=ll; }
  *(u16x8*)hp = h; *(u16x8*)lp = l;
}
__device__ __forceinline__ void cvt8(const float* __restrict__ s,
                                     u16* __restrict__ hp, u16* __restrict__ lp){
  F8 x = ld8(s);
  st8bf(hp, lp, x);
}

__device__ __forceinline__ F8 mobius_add8(const F8& x, const F8& y){
  float x2 = wredsum(ssq8(x));
  float y2 = wredsum(ssq8(y));
  float d = 0.f;
#pragma unroll
  for(int i=0;i<8;i++) d = fmaf(x.v[i], y.v[i], d);
  float xy = wredsum(d);
  float cx  = 1.f + 2.f*xy + y2;
  float cy  = 1.f - x2;
  float den = fmaxf(1.f + 2.f*xy + x2*y2, EPSf);
  F8 z;
#pragma unroll
  for(int i=0;i<8;i++) z.v[i] = (cx*x.v[i] + cy*y.v[i]) / den;
  float s2 = wredsum(ssq8(z));
  float n  = sqrtf(fmaxf(s2, EPS2f));
  float pr = fminf(1.f, MAXNf/n);
#pragma unroll
  for(int i=0;i<8;i++) z.v[i] *= pr;
  return z;
}

// ---------------- elementwise / row kernels ----------------

__global__ void k_mobius_pos(const float* __restrict__ xin, const float* __restrict__ pos,
                             float* __restrict__ xout){
  const int r = blockIdx.x, lane = threadIdx.x;
  const int s = r % S_;
  const size_t o = (size_t)r*D_ + (lane<<3);
  F8 x = ld8(xin + o);
  F8 y = ld8(pos + (size_t)s*D_ + (lane<<3));
  F8 z = mobius_add8(x, y);
  st8(xout + o, z);
}

// u = sum of KSG_ partials; h = expmap0(u); x = mobius_add(x, h)
__global__ void k_mobius_epi(const float* __restrict__ up, float* __restrict__ x){
  const int r = blockIdx.x, lane = threadIdx.x;
  const size_t o = (size_t)r*D_ + (lane<<3);
  F8 u = ld8(up + o);
  for(int ks=1; ks<KSG_; ks++){
    F8 t = ld8(up + (size_t)ks*N_*D_ + o);
#pragma unroll
    for(int i=0;i<8;i++) u.v[i] += t.v[i];
  }
  float s2 = wredsum(ssq8(u));
  float n  = sqrtf(fmaxf(s2, EPS2f));
  float se = tanhf(n)/n;
#pragma unroll
  for(int i=0;i<8;i++) u.v[i] *= se;
  F8 xv = ld8(x + o);
  F8 z = mobius_add8(xv, u);
  st8(x + o, z);
}

// fused pln -> tangent (bf16 hi/lo out)
__global__ void k_pln_tan(const float* __restrict__ xin, const float* __restrict__ w,
                          const float* __restrict__ b, u16* __restrict__ th,
                          u16* __restrict__ tl){
  const int r = blockIdx.x, lane = threadIdx.x;
  const size_t o = (size_t)r*D_ + (lane<<3);
  F8 x = ld8(xin + o);
  float s2 = wredsum(ssq8(x));
  float n  = sqrtf(fmaxf(s2, EPS2f));
  float nc = fminf(fmaxf(n, EPSf), MAXNf);
  float a  = atanhf(nc)/nc;
  F8 t;
#pragma unroll
  for(int i=0;i<8;i++) t.v[i] = x.v[i]*a;
  float mu = wredsum(sum8(t)) * (1.f/(float)D_);
#pragma unroll
  for(int i=0;i<8;i++) t.v[i] -= mu;
  float var = wredsum(ssq8(t)) * (1.f/(float)D_);
  float inv = 1.f/sqrtf(var + 1e-5f);
  F8 wv = ld8(w + (lane<<3));
  F8 bv = ld8(b + (lane<<3));
  F8 u;
#pragma unroll
  for(int i=0;i<8;i++) u.v[i] = fmaf(t.v[i]*inv, wv.v[i], bv.v[i]);
  float s2u = wredsum(ssq8(u));
  float nu  = sqrtf(fmaxf(s2u, EPS2f));
  float se  = tanhf(nu)/nu;
#pragma unroll
  for(int i=0;i<8;i++) u.v[i] *= se;
  float s2p = wredsum(ssq8(u));
  float npn = sqrtf(fmaxf(s2p, EPS2f));
  float nc2 = fminf(fmaxf(npn, EPSf), MAXNf);
  float al  = atanhf(nc2)/nc2;
#pragma unroll
  for(int i=0;i<8;i++) u.v[i] *= al;
  st8bf(th + o, tl + o, u);
}

// t = logmap0(p) -> bf16 hi/lo
__global__ void k_logmap(const float* __restrict__ in, u16* __restrict__ th,
                         u16* __restrict__ tl){
  const int r = blockIdx.x, lane = threadIdx.x;
  const size_t o = (size_t)r*D_ + (lane<<3);
  F8 x = ld8(in + o);
  float s2 = wredsum(ssq8(x));
  float n  = sqrtf(fmaxf(s2, EPS2f));
  float nc = fminf(fmaxf(n, EPSf), MAXNf);
  float a  = atanhf(nc)/nc;
#pragma unroll
  for(int i=0;i<8;i++) x.v[i] *= a;
  st8bf(th + o, tl + o, x);
}

// sum KSG_ partials -> expmap0 -> logmap0 -> *betaS -> per-head expmap0 -> head layout
__global__ void k_split(const float* __restrict__ up, float* __restrict__ vout,
                        float* __restrict__ aux, int mode, float betaS){
  const int r = blockIdx.x, lane = threadIdx.x;
  const int b = r / S_, s = r % S_;
  const size_t o = (size_t)r*D_ + (lane<<3);
  F8 u = ld8(up + o);
  for(int ks=1; ks<KSG_; ks++){
    F8 t = ld8(up + (size_t)ks*N_*D_ + o);
#pragma unroll
    for(int i=0;i<8;i++) u.v[i] += t.v[i];
  }
  float s2u = wredsum(ssq8(u));
  float n   = sqrtf(fmaxf(s2u, EPS2f));
  float se  = tanhf(n)/n;
#pragma unroll
  for(int i=0;i<8;i++) u.v[i] *= se;
  float s2p = wredsum(ssq8(u));
  float np  = sqrtf(fmaxf(s2p, EPS2f));
  float nc  = fminf(fmaxf(np, EPSf), MAXNf);
  float al  = atanhf(nc)/nc * betaS;
#pragma unroll
  for(int i=0;i<8;i++) u.v[i] *= al;
  float s2h = g8sum(ssq8(u));
  float nh  = sqrtf(fmaxf(s2h, EPS2f));
  float sh  = tanhf(nh)/nh;
#pragma unroll
  for(int i=0;i<8;i++) u.v[i] *= sh;
  const int head = lane>>3, d0 = (lane&7)<<3;
  const size_t ho = ((size_t)(b*H_+head)*S_ + s)*HD_ + d0;
  if (mode == 2){
    float v2  = g8sum(ssq8(u));
    float lam = 2.f/fmaxf(1.f - v2, EPSf);
    F8 lv;
#pragma unroll
    for(int i=0;i<8;i++) lv.v[i] = u.v[i]*lam;
    st8(vout + ho, lv);
    if((lane&7)==0) aux[(size_t)(b*H_+head)*S_ + s] = lam - 1.f;
  } else {
    st8(vout + ho, u);
    if(mode == 1){
      float k2 = g8sum(ssq8(u));
      if((lane&7)==0) aux[(size_t)(b*H_+head)*S_ + s] = k2;
    }
  }
}

// ---------------- attention ----------------
#define AST 68
__global__ __launch_bounds__(256) void k_attn(
    const float* __restrict__ qh, const float* __restrict__ kh,
    const float* __restrict__ k2a, const float* __restrict__ lamv,
    const float* __restrict__ lm1, const float* __restrict__ taup,
    const float* __restrict__ gamp, float* __restrict__ nump,
    float* __restrict__ denp){
  const int bid = blockIdx.x;
  const int bh  = bid >> 6;
  const int qt  = (bid & 63) >> 2;
  const int ks  = bid & 3;
  if ((ks<<2) > qt) return;
  const int tid  = threadIdx.x;
  const int w    = tid >> 6;
  const int lane = tid & 63;
  const int i    = (qt<<6) + lane;
  const float tau = *taup, gam = *gamp;
  __shared__ float Ks[64*AST];
  __shared__ float Vs[64*AST];
  __shared__ float k2s[64];
  __shared__ float l1s[64];
  __shared__ float dden[4][64];
  const float4* qp = (const float4*)(qh + ((size_t)bh*S_ + i)*HD_);
  float4 q[16];
#pragma unroll
  for(int c=0;c<16;c++) q[c] = qp[c];
  float q2 = 0.f;
#pragma unroll
  for(int c=0;c<16;c++){
    q2 = fmaf(q[c].x,q[c].x,q2); q2 = fmaf(q[c].y,q[c].y,q2);
    q2 = fmaf(q[c].z,q[c].z,q2); q2 = fmaf(q[c].w,q[c].w,q2);
  }
  const float omq = 1.f - q2;
  float4 acc[16];
#pragma unroll
  for(int c=0;c<16;c++) acc[c] = make_float4(0.f,0.f,0.f,0.f);
  float dacc = 0.f;
  const int jmax = i;
  for(int kt=0; kt<4; kt++){
    const int j0 = (ks<<8) + (kt<<6);
    if (j0 > (qt<<6)) break;
    __syncthreads();
    const float4* kp = (const float4*)(kh   + ((size_t)bh*S_ + j0)*HD_);
    const float4* vp = (const float4*)(lamv + ((size_t)bh*S_ + j0)*HD_);
#pragma unroll
    for(int it=0; it<4; it++){
      const int f   = (it<<8) + tid;
      const int row = f >> 4, c4 = f & 15;
      ((float4*)(Ks + row*AST))[c4] = kp[f];
      ((float4*)(Vs + row*AST))[c4] = vp[f];
    }
    if (tid < 64)      k2s[tid]     = k2a[(size_t)bh*S_ + j0 + tid];
    else if (tid <128) l1s[tid-64]  = lm1[(size_t)bh*S_ + j0 + tid - 64];
    __syncthreads();
    for(int jj=0; jj<16; jj++){
      const int j = (w<<4) + jj;
      const float4* kr = (const float4*)(Ks + j*AST);
      float dp[4] = {0.f,0.f,0.f,0.f};
#pragma unroll
      for(int c=0;c<16;c++){
        const float4 k4 = kr[c];
        float d = dp[c&3];
        d = fmaf(q[c].x,k4.x,d); d = fmaf(q[c].y,k4.y,d);
        d = fmaf(q[c].z,k4.z,d); d = fmaf(q[c].w,k4.w,d);
        dp[c&3] = d;
      }
      const float dot  = (dp[0]+dp[1]) + (dp[2]+dp[3]);
      const float k2v  = k2s[j];
      const float d2   = fmaxf(q2 + k2v - 2.f*dot, 0.f);
      const float dn   = fmaxf(omq*(1.f-k2v), EPSf);
      const float z    = fmaxf(1.f + 2.f*d2/dn, 1.f + 1e-7f);
      const float dist = __logf(z + __fsqrt_rn(fmaf(z,z,-1.f)));
      const float wgt  = (j0 + j <= jmax) ? __expf(fmaf(-tau, dist, -gam)) : 0.f;
      dacc = fmaf(wgt, l1s[j], dacc);
      const float4* vr = (const float4*)(Vs + j*AST);
#pragma unroll
      for(int c=0;c<16;c++){
        const float4 v4 = vr[c];
        acc[c].x = fmaf(wgt, v4.x, acc[c].x);
        acc[c].y = fmaf(wgt, v4.y, acc[c].y);
        acc[c].z = fmaf(wgt, v4.z, acc[c].z);
        acc[c].w = fmaf(wgt, v4.w, acc[c].w);
      }
    }
  }
  __syncthreads();
  dden[w][lane] = dacc;
  if (w==1){ float4* p=(float4*)(Ks + lane*AST);
#pragma unroll
    for(int c=0;c<16;c++) p[c]=acc[c]; }
  if (w==3){ float4* p=(float4*)(Vs + lane*AST);
#pragma unroll
    for(int c=0;c<16;c++) p[c]=acc[c]; }
  __syncthreads();
  if (w==0){ const float4* p=(const float4*)(Ks + lane*AST);
#pragma unroll
    for(int c=0;c<16;c++){ float4 t=p[c];
      acc[c].x+=t.x; acc[c].y+=t.y; acc[c].z+=t.z; acc[c].w+=t.w; }
    dacc += dden[1][lane]; }
  if (w==2){ const float4* p=(const float4*)(Vs + lane*AST);
#pragma unroll
    for(int c=0;c<16;c++){ float4 t=p[c];
      acc[c].x+=t.x; acc[c].y+=t.y; acc[c].z+=t.z; acc[c].w+=t.w; }
    dacc += dden[3][lane]; }
  __syncthreads();
  if (w==2){ float4* p=(float4*)(Ks + lane*AST);
#pragma unroll
    for(int c=0;c<16;c++) p[c]=acc[c];
    dden[2][lane] = dacc; }
  __syncthreads();
  if (w==0){
    const float4* p=(const float4*)(Ks + lane*AST);
#pragma unroll
    for(int c=0;c<16;c++){ float4 t=p[c];
      acc[c].x+=t.x; acc[c].y+=t.y; acc[c].z+=t.z; acc[c].w+=t.w; }
    dacc += dden[2][lane];
    float4* np = (float4*)(nump + ((size_t)ks*BHS_ + (size_t)bh*S_ + i)*HD_);
#pragma unroll
    for(int c=0;c<16;c++) np[c] = acc[c];
    denp[(size_t)ks*BHS_ + (size_t)bh*S_ + i] = dacc;
  }
}

__global__ void k_combine(const float* __restrict__ nump, const float* __restrict__ denp,
                          float* __restrict__ pout, float betaC){
  const int r = blockIdx.x, lane = threadIdx.x;
  const int b = r / S_, s = r % S_;
  const int nks  = (s >> 8) + 1;
  const int head = lane >> 3;
  const int d0   = (lane & 7) << 3;
  const size_t hrow = (size_t)(b*H_ + head)*S_ + s;
  F8 num;
#pragma unroll
  for(int i=0;i<8;i++) num.v[i]=0.f;
  float den = 0.f;
  for(int ks=0; ks<nks; ks++){
    F8 t = ld8(nump + ((size_t)ks*BHS_ + hrow)*HD_ + d0);
#pragma unroll
    for(int i=0;i<8;i++) num.v[i] += t.v[i];
    den += denp[(size_t)ks*BHS_ + hrow];
  }
  den = fmaxf(den, EPSf);
  F8 y;
#pragma unroll
  for(int i=0;i<8;i++) y.v[i] = num.v[i]/den;
  float s2 = g8sum(ssq8(y));
  float n  = fminf(fmaxf(sqrtf(fmaxf(s2,EPS2f)), EPSf), MAXNf);
  float ms = tanhf(0.5f*atanhf(n))/n;
#pragma unroll
  for(int i=0;i<8;i++) y.v[i] *= ms;
  float s2y = g8sum(ssq8(y));
  float ny  = sqrtf(fmaxf(s2y, EPS2f));
  float pf  = fminf(1.f, MAXNf/ny);
#pragma unroll
  for(int i=0;i<8;i++) y.v[i] *= pf;
  float s2c = g8sum(ssq8(y));
  float np2 = sqrtf(fmaxf(s2c, EPS2f));
  float ncc = fminf(fmaxf(np2, EPSf), MAXNf);
  float al  = atanhf(ncc)/ncc * betaC;
#pragma unroll
  for(int i=0;i<8;i++) y.v[i] *= al;
  float s2t = wredsum(ssq8(y));
  float nt  = sqrtf(fmaxf(s2t, EPS2f));
  float se  = tanhf(nt)/nt;
#pragma unroll
  for(int i=0;i<8;i++) y.v[i] *= se;
  st8(pout + (size_t)r*D_ + head*HD_ + d0, y);
}

// FFN middle: sum 2 partials -> expmap -> logmap -> relu -> expmap -> logmap -> bf16 hi/lo
__global__ void k_ffn_mid(const float* __restrict__ u, u16* __restrict__ th,
                          u16* __restrict__ tl){
  const int r = blockIdx.x, lane = threadIdx.x;
  const float* p0 = u + (size_t)r*FF_ + (lane<<5);
  const float* p1 = p0 + (size_t)N_*FF_;
  float4 x[8];
#pragma unroll
  for(int c=0;c<8;c++){
    float4 a = *(const float4*)(p0 + (c<<2));
    float4 b = *(const float4*)(p1 + (c<<2));
    x[c] = make_float4(a.x+b.x, a.y+b.y, a.z+b.z, a.w+b.w);
  }
  float ls;
#define SSQ8x4(out) { out=0.f; _Pragma("unroll") for(int c=0;c<8;c++){ out=fmaf(x[c].x,x[c].x,out); out=fmaf(x[c].y,x[c].y,out); out=fmaf(x[c].z,x[c].z,out); out=fmaf(x[c].w,x[c].w,out);} }
#define SCALE8x4(a) { _Pragma("unroll") for(int c=0;c<8;c++){ x[c].x*=(a); x[c].y*=(a); x[c].z*=(a); x[c].w*=(a);} }
  SSQ8x4(ls);
  float s2 = wredsum(ls);
  float n  = sqrtf(fmaxf(s2, EPS2f));
  SCALE8x4(tanhf(n)/n);
  SSQ8x4(ls); s2 = wredsum(ls);
  n = sqrtf(fmaxf(s2, EPS2f));
  float nc = fminf(fmaxf(n, EPSf), MAXNf);
  SCALE8x4(atanhf(nc)/nc);
#pragma unroll
  for(int c=0;c<8;c++){
    x[c].x=fmaxf(x[c].x,0.f); x[c].y=fmaxf(x[c].y,0.f);
    x[c].z=fmaxf(x[c].z,0.f); x[c].w=fmaxf(x[c].w,0.f);
  }
  SSQ8x4(ls); s2 = wredsum(ls);
  n = sqrtf(fmaxf(s2, EPS2f));
  SCALE8x4(tanhf(n)/n);
  SSQ8x4(ls); s2 = wredsum(ls);
  n = sqrtf(fmaxf(s2, EPS2f));
  nc = fminf(fmaxf(n, EPSf), MAXNf);
  SCALE8x4(atanhf(nc)/nc);
  u16* hp = th + (size_t)r*FF_ + (lane<<5);
  u16* lp = tl + (size_t)r*FF_ + (lane<<5);
#pragma unroll
  for(int cc=0; cc<4; cc++){
    F8 f;
    f.v[0]=x[2*cc].x; f.v[1]=x[2*cc].y; f.v[2]=x[2*cc].z; f.v[3]=x[2*cc].w;
    f.v[4]=x[2*cc+1].x; f.v[5]=x[2*cc+1].y; f.v[6]=x[2*cc+1].z; f.v[7]=x[2*cc+1].w;
    st8bf(hp + (cc<<3), lp + (cc<<3), f);
  }
#undef SSQ8x4
#undef SCALE8x4
}

__global__ void k_final(const float* __restrict__ up, float* __restrict__ out){
  const int r = blockIdx.x, lane = threadIdx.x;
  const size_t o = (size_t)r*D_ + (lane<<3);
  F8 u = ld8(up + o);
  for(int ks=1; ks<KSG_; ks++){
    F8 t = ld8(up + (size_t)ks*N_*D_ + o);
#pragma unroll
    for(int i=0;i<8;i++) u.v[i] += t.v[i];
  }
  float s2 = wredsum(ssq8(u));
  float n  = sqrtf(fmaxf(s2, EPS2f));
  float se = tanhf(n)/n;
#pragma unroll
  for(int i=0;i<8;i++) u.v[i] *= se;
  st8(out + o, u);
}

// ---------------- weight conversion ----------------
// wbuf layout (ushort offsets): QKVO t=0..3: h at t*524288, l at +262144;
// W1 h 2097152 l 3145728; W2 h 4194304 l 5242880.
__global__ void k_cvt6(const float* __restrict__ Wq, const float* __restrict__ Wk,
                       const float* __restrict__ Wv, const float* __restrict__ Wo,
                       const float* __restrict__ W1, const float* __restrict__ W2,
                       u16* __restrict__ wb){
  const int t = blockIdx.y;
  const int n = (t<4) ? (D_*D_) : (FF_*D_);
  const int idx = (int)((blockIdx.x*256 + threadIdx.x)<<3);
  if (idx >= n) return;
  const float* src; u16 *hp, *lp;
  switch(t){
    case 0: src=Wq; hp=wb;          lp=wb+262144;  break;
    case 1: src=Wk; hp=wb+524288;   lp=wb+786432;  break;
    case 2: src=Wv; hp=wb+1048576;  lp=wb+1310720; break;
    case 3: src=Wo; hp=wb+1572864;  lp=wb+1835008; break;
    case 4: src=W1; hp=wb+2097152;  lp=wb+3145728; break;
    default:src=W2; hp=wb+4194304;  lp=wb+5242880; break;
  }
  cvt8(src+idx, hp+idx, lp+idx);
}
__global__ void k_cvt1(const float* __restrict__ src, u16* __restrict__ hp,
                       u16* __restrict__ lp){
  const int idx = (int)((blockIdx.x*256 + threadIdx.x)<<3);
  cvt8(src+idx, hp+idx, lp+idx);
}

// ---------------- MFMA GEMM ----------------
// C[ks][n][m] (+bias at ks==0) = A[n][k]*W[m][k]^T over this split's k-range,
// where A ~ Ah+Al, W ~ Wh+Wl (bf16 hi/lo), product = Ah*Wh + Ah*Wl + Al*Wh.
// 256 threads = 4 waves (2x2), 128x128 tile, BK=64. LDS 64KB, XOR-swizzled
// (chunk ^= row&7 on 16B chunks) via pre-swizzled global source (rule #21).
#define SAH 0
#define SAL 8192
#define SWH 16384
#define SWL 24576
__device__ __forceinline__ void gll16(const void* g, void* l){
  __builtin_amdgcn_global_load_lds((const __attribute__((address_space(1))) void*)g,
                                   (__attribute__((address_space(3))) void*)l, 16, 0, 0);
}
__global__ __launch_bounds__(256) void k_gemm_mfma(
    const u16* __restrict__ Ah, const u16* __restrict__ Al,
    const u16* __restrict__ Wh, const u16* __restrict__ Wl,
    const float* __restrict__ bias, float* __restrict__ C,
    int K, int M, int kslen){
  __shared__ u16 lds[32768];
  const int tid = threadIdx.x;
  const int wv = tid>>6, lane = tid&63;
  const int wr = wv>>1, wc = wv&1;
  const int lhi = lane>>4, llo = lane&15;
  const int m0 = blockIdx.x<<7;
  const int n0 = blockIdx.y<<7;
  const int ks = blockIdx.z;
  f32x4 acc[4][4];
#pragma unroll
  for(int i=0;i<4;i++)
#pragma unroll
    for(int j=0;j<4;j++) acc[i][j] = (f32x4){0.f,0.f,0.f,0.f};
  const int sr = lane>>3;              // 0..7 staged row within 8-row group
  const int g  = (lane&7) ^ sr;        // pre-swizzled global 16B-chunk
  const int kend = (ks+1)*kslen;
  for(int k0 = ks*kslen; k0 < kend; k0 += 64){
    __syncthreads();
#pragma unroll
    for(int t=0;t<4;t++){
      const int row = wv*32 + t*8 + sr;
      const int lo  = (wv*4+t)*512;    // ushorts (1KB per instr)
      const size_t ga = (size_t)(n0+row)*K + k0 + g*8;
      const size_t gw = (size_t)(m0+row)*K + k0 + g*8;
      gll16(Ah + ga, &lds[SAH+lo]);
      gll16(Al + ga, &lds[SAL+lo]);
      gll16(Wh + gw, &lds[SWH+lo]);
      gll16(Wl + gw, &lds[SWL+lo]);
    }
    __syncthreads();
#pragma unroll
    for(int kc=0;kc<2;kc++){
      s16x8 ah[4], al4[4], wh4[4], wl4[4];
#pragma unroll
      for(int f=0;f<4;f++){
        const int ra = wr*64 + f*16 + llo;
        const int rw = wc*64 + f*16 + llo;
        const int ca = (kc*4 + lhi) ^ (llo&7);
        ah[f]  = *(const s16x8*)&lds[SAH + ra*64 + ca*8];
        al4[f] = *(const s16x8*)&lds[SAL + ra*64 + ca*8];
        wh4[f] = *(const s16x8*)&lds[SWH + rw*64 + ca*8];
        wl4[f] = *(const s16x8*)&lds[SWL + rw*64 + ca*8];
      }
#pragma unroll
      for(int i=0;i<4;i++)
#pragma unroll
        for(int j=0;j<4;j++){
          acc[i][j] = __builtin_amdgcn_mfma_f32_16x16x32_bf16(ah[i],  wh4[j], acc[i][j], 0,0,0);
          acc[i][j] = __builtin_amdgcn_mfma_f32_16x16x32_bf16(ah[i],  wl4[j], acc[i][j], 0,0,0);
          acc[i][j] = __builtin_amdgcn_mfma_f32_16x16x32_bf16(al4[i], wh4[j], acc[i][j], 0,0,0);
        }
    }
  }
  const size_t cbase = (size_t)ks*(size_t)N_*M;
  float bload[4];
#pragma unroll
  for(int j=0;j<4;j++)
    bload[j] = (ks==0) ? bias[m0 + wc*64 + j*16 + llo] : 0.f;
#pragma unroll
  for(int i=0;i<4;i++)
#pragma unroll
    for(int r=0;r<4;r++){
      const int n = n0 + wr*64 + i*16 + lhi*4 + r;
      float* cp = C + cbase + (size_t)n*M + m0 + wc*64 + llo;
#pragma unroll
      for(int j=0;j<4;j++) cp[j*16] = acc[i][j][r] + bload[j];
    }
}

// ---------------- host ----------------
extern "C" void kernel_launch(void* const* d_in, const int* in_sizes, int n_in,
                              void* d_out, int out_size, void* d_ws, size_t ws_size,
                              hipStream_t stream){
  const float* x_in = (const float*)d_in[0];
  const float* pos  = (const float*)d_in[1];
  const float* ln1w = (const float*)d_in[2];
  const float* ln1b = (const float*)d_in[3];
  const float* ln2w = (const float*)d_in[4];
  const float* ln2b = (const float*)d_in[5];
  const float* Wq   = (const float*)d_in[6];
  const float* bq   = (const float*)d_in[7];
  const float* Wk   = (const float*)d_in[8];
  const float* bk   = (const float*)d_in[9];
  const float* Wv   = (const float*)d_in[10];
  const float* bv   = (const float*)d_in[11];
  const float* Wo   = (const float*)d_in[12];
  const float* bo   = (const float*)d_in[13];
  const float* W1   = (const float*)d_in[14];
  const float* b1   = (const float*)d_in[15];
  const float* W2   = (const float*)d_in[16];
  const float* b2   = (const float*)d_in[17];
  const float* tau  = (const float*)d_in[18];
  const float* gam  = (const float*)d_in[19];
  const float* Wout = (const float*)d_in[20];
  const float* bout = (const float*)d_in[21];

  float* ws = (float*)d_ws;
  float* xb  = ws;                              // [N,D] fp32
  float* ub  = xb  + (size_t)N_*D_;             // [8,N,512] or [2,N,2048] fp32 GEMM partials; aliased attn nump
  float* qhb = ub  + (size_t)KSG_*N_*D_;        // [B,H,S,HD]; aliased p_att
  float* khb = qhb + (size_t)N_*D_;
  float* lvb = khb + (size_t)N_*D_;             // lam*v
  float* k2b = lvb + (size_t)N_*D_;             // [B,H,S]
  float* l1b = k2b + (size_t)BHS_;              // [B,H,S]
  float* dnb = l1b + (size_t)BHS_;              // [KSA,B,H,S]
  u16*   tbh = (u16*)(dnb + (size_t)KSA_*BHS_); // [N,FF] bf16 hi
  u16*   tbl = tbh + (size_t)N_*FF_;            // [N,FF] bf16 lo
  u16*   wb  = tbl + (size_t)N_*FF_;            // 6291456 ushorts weight hi/lo
  float* nump = ub;
  float* patt = qhb;

  const double bd  = exp(lgamma(D_/2.0)  + lgamma(0.5) - lgamma(D_/2.0  + 0.5));
  const double bhd = exp(lgamma(HD_/2.0) + lgamma(0.5) - lgamma(HD_/2.0 + 0.5));
  const float betaS = (float)(bhd/bd);
  const float betaC = (float)(bd/bhd);

  const dim3 g512(4, 16, KSG_);     // M=512 GEMMs: 512 blocks
  const dim3 gff1(16, 16, KSF_);    // M=2048, K=512: 512 blocks
  const dim3 gcv(512, 6);

  k_mobius_pos<<<N_,64,0,stream>>>(x_in, pos, xb);
  for(int l=0; l<L_; l++){
    k_cvt6<<<gcv,256,0,stream>>>(Wq + (size_t)l*D_*D_, Wk + (size_t)l*D_*D_,
                                 Wv + (size_t)l*D_*D_, Wo + (size_t)l*D_*D_,
                                 W1 + (size_t)l*FF_*D_, W2 + (size_t)l*D_*FF_, wb);
    k_pln_tan<<<N_,64,0,stream>>>(xb, ln1w + l*D_, ln1b + l*D_, tbh, tbl);
    k_gemm_mfma<<<g512,256,0,stream>>>(tbh, tbl, wb,          wb+262144,  bq + l*D_, ub, 512, 512, 64);
    k_split<<<N_,64,0,stream>>>(ub, qhb, k2b /*unused*/, 0, betaS);
    k_gemm_mfma<<<g512,256,0,stream>>>(tbh, tbl, wb+524288,   wb+786432,  bk + l*D_, ub, 512, 512, 64);
    k_split<<<N_,64,0,stream>>>(ub, khb, k2b, 1, betaS);
    k_gemm_mfma<<<g512,256,0,stream>>>(tbh, tbl, wb+1048576,  wb+1310720, bv + l*D_, ub, 512, 512, 64);
    k_split<<<N_,64,0,stream>>>(ub, lvb, l1b, 2, betaS);
    k_attn<<<1024,256,0,stream>>>(qhb, khb, k2b, lvb, l1b, tau + l, gam + l, nump, dnb);
    k_combine<<<N_,64,0,stream>>>(nump, dnb, patt, betaC);
    k_logmap<<<N_,64,0,stream>>>(patt, tbh, tbl);
    k_gemm_mfma<<<g512,256,0,stream>>>(tbh, tbl, wb+1572864,  wb+1835008, bo + l*D_, ub, 512, 512, 64);
    k_mobius_epi<<<N_,64,0,stream>>>(ub, xb);
    k_pln_tan<<<N_,64,0,stream>>>(xb, ln2w + l*D_, ln2b + l*D_, tbh, tbl);
    k_gemm_mfma<<<gff1,256,0,stream>>>(tbh, tbl, wb+2097152,  wb+3145728, b1 + l*FF_, ub, 512, 2048, 256);
    k_ffn_mid<<<N_,64,0,stream>>>(ub, tbh, tbl);
    k_gemm_mfma<<<g512,256,0,stream>>>(tbh, tbl, wb+4194304,  wb+5242880, b2 + l*D_, ub, 2048, 512, 256);
    k_mobius_epi<<<N_,64,0,stream>>>(ub, xb);
  }
  k_logmap<<<N_,64,0,stream>>>(xb, tbh, tbl);
  k_cvt1<<<128,256,0,stream>>>(Wout, wb, wb+262144);
  k_gemm_mfma<<<g512,256,0,stream>>>(tbh, tbl, wb, wb+262144, bout, ub, 512, 512, 64);
  k_final<<<N_,64,0,stream>>>(ub, (float*)d_out);
}

// Round 8
// 1058.948 us; speedup vs baseline: 2.8906x; 1.2369x over previous
//
#include <hip/hip_runtime.h>
#include <cmath>

// Poincare-ball causal transformer forward, MI355X.
// GEMMs + attention QK^T/PV via bf16 hi/lo 3-product MFMA (fp32-faithful).
// k_attn stages all LDS via plain ds_write (no global_load_lds) to avoid
// async-DMA/barrier interplay in the multi-phase pipeline; GEMM keeps gll16
// (replay-proven in round 4).
#define B_ 2
#define S_ 1024
#define D_ 512
#define H_ 8
#define HD_ 64
#define FF_ 2048
#define L_ 4
#define N_ (B_*S_)          // 2048 token rows
#define BHS_ (B_*H_*S_)     // 16384 head rows
#define EPSf 1e-7f
#define EPS2f 1e-14f
#define MAXNf 0.999f
#define KSG_ 8              // split-K partials for M=512 MFMA GEMMs
#define KSF_ 2              // split-K partials for FF1 (M=2048)
#define KSA_ 4              // attention key splits

typedef unsigned short u16;
typedef __attribute__((ext_vector_type(8))) short s16x8;           // 8 bf16 (x32 MFMA A/B)
typedef __attribute__((ext_vector_type(4))) short s16x4;
typedef __attribute__((ext_vector_type(8))) unsigned short u16x8;
typedef __attribute__((ext_vector_type(4))) float f32x4;           // MFMA C/D frag

// ---------------- small helpers ----------------
struct F8 { float v[8]; };

__device__ __forceinline__ F8 ld8(const float* __restrict__ p){
  F8 r; const float4 a = *(const float4*)p; const float4 b = *(const float4*)(p+4);
  r.v[0]=a.x; r.v[1]=a.y; r.v[2]=a.z; r.v[3]=a.w;
  r.v[4]=b.x; r.v[5]=b.y; r.v[6]=b.z; r.v[7]=b.w;
  return r;
}
__device__ __forceinline__ void st8(float* __restrict__ p, const F8& r){
  *(float4*)p     = make_float4(r.v[0],r.v[1],r.v[2],r.v[3]);
  *(float4*)(p+4) = make_float4(r.v[4],r.v[5],r.v[6],r.v[7]);
}
__device__ __forceinline__ float ssq8(const F8& r){
  float s=0.f;
#pragma unroll
  for(int i=0;i<8;i++) s = fmaf(r.v[i], r.v[i], s);
  return s;
}
__device__ __forceinline__ float sum8(const F8& r){
  float s=0.f;
#pragma unroll
  for(int i=0;i<8;i++) s += r.v[i];
  return s;
}
__device__ __forceinline__ float wredsum(float v){
#pragma unroll
  for(int o=1;o<64;o<<=1) v += __shfl_xor(v,o,64);
  return v;
}
__device__ __forceinline__ float g8sum(float v){
#pragma unroll
  for(int o=1;o<8;o<<=1) v += __shfl_xor(v,o,64);
  return v;
}

// bf16 hi/lo split: hi = RN(x), lo = RN(x - hi); x-hi is exact in fp32.
__device__ __forceinline__ void bfsplit(float x, u16& h, u16& l){
  unsigned u = __float_as_uint(x);
  h = (u16)((u + 0x7FFFu + ((u>>16)&1u))>>16);
  float back = __uint_as_float(((unsigned)h)<<16);
  float r = x - back;
  unsigned u2 = __float_as_uint(r);
  l = (u16)((u2 + 0x7FFFu + ((u2>>16)&1u))>>16);
}
__device__ __forceinline__ void st8bf(u16* __restrict__ hp, u16* __restrict__ lp, const F8& r){
  u16x8 h, l;
#pragma unroll
  for(int i=0;i<8;i++){ u16 hh,ll; bfsplit(r.v[i],hh,ll); h[i]=hh; l[i]=ll; }
  *(u16x8*)hp = h; *(u16x8*)lp = l;
}
__device__ __forceinline__ void cvt8(const float* __restrict__ s,
                                     u16* __restrict__ hp, u16* __restrict__ lp){
  F8 x = ld8(s);
  st8bf(hp, lp, x);
}

__device__ __forceinline__ F8 mobius_add8(const F8& x, const F8& y){
  float x2 = wredsum(ssq8(x));
  float y2 = wredsum(ssq8(y));
  float d = 0.f;
#pragma unroll
  for(int i=0;i<8;i++) d = fmaf(x.v[i], y.v[i], d);
  float xy = wredsum(d);
  float cx  = 1.f + 2.f*xy + y2;
  float cy  = 1.f - x2;
  float den = fmaxf(1.f + 2.f*xy + x2*y2, EPSf);
  F8 z;
#pragma unroll
  for(int i=0;i<8;i++) z.v[i] = (cx*x.v[i] + cy*y.v[i]) / den;
  float s2 = wredsum(ssq8(z));
  float n  = sqrtf(fmaxf(s2, EPS2f));
  float pr = fminf(1.f, MAXNf/n);
#pragma unroll
  for(int i=0;i<8;i++) z.v[i] *= pr;
  return z;
}

__device__ __forceinline__ void gll16(const void* g, void* l){
  __builtin_amdgcn_global_load_lds((const __attribute__((address_space(1))) void*)g,
                                   (__attribute__((address_space(3))) void*)l, 16, 0, 0);
}

// ---------------- elementwise / row kernels ----------------

__global__ void k_mobius_pos(const float* __restrict__ xin, const float* __restrict__ pos,
                             float* __restrict__ xout){
  const int r = blockIdx.x, lane = threadIdx.x;
  const int s = r % S_;
  const size_t o = (size_t)r*D_ + (lane<<3);
  F8 x = ld8(xin + o);
  F8 y = ld8(pos + (size_t)s*D_ + (lane<<3));
  F8 z = mobius_add8(x, y);
  st8(xout + o, z);
}

// u = sum of KSG_ partials; h = expmap0(u); x = mobius_add(x, h)
__global__ void k_mobius_epi(const float* __restrict__ up, float* __restrict__ x){
  const int r = blockIdx.x, lane = threadIdx.x;
  const size_t o = (size_t)r*D_ + (lane<<3);
  F8 u = ld8(up + o);
  for(int ks=1; ks<KSG_; ks++){
    F8 t = ld8(up + (size_t)ks*N_*D_ + o);
#pragma unroll
    for(int i=0;i<8;i++) u.v[i] += t.v[i];
  }
  float s2 = wredsum(ssq8(u));
  float n  = sqrtf(fmaxf(s2, EPS2f));
  float se = tanhf(n)/n;
#pragma unroll
  for(int i=0;i<8;i++) u.v[i] *= se;
  F8 xv = ld8(x + o);
  F8 z = mobius_add8(xv, u);
  st8(x + o, z);
}

// fused pln -> tangent (bf16 hi/lo out)
__global__ void k_pln_tan(const float* __restrict__ xin, const float* __restrict__ w,
                          const float* __restrict__ b, u16* __restrict__ th,
                          u16* __restrict__ tl){
  const int r = blockIdx.x, lane = threadIdx.x;
  const size_t o = (size_t)r*D_ + (lane<<3);
  F8 x = ld8(xin + o);
  float s2 = wredsum(ssq8(x));
  float n  = sqrtf(fmaxf(s2, EPS2f));
  float nc = fminf(fmaxf(n, EPSf), MAXNf);
  float a  = atanhf(nc)/nc;
  F8 t;
#pragma unroll
  for(int i=0;i<8;i++) t.v[i] = x.v[i]*a;
  float mu = wredsum(sum8(t)) * (1.f/(float)D_);
#pragma unroll
  for(int i=0;i<8;i++) t.v[i] -= mu;
  float var = wredsum(ssq8(t)) * (1.f/(float)D_);
  float inv = 1.f/sqrtf(var + 1e-5f);
  F8 wv = ld8(w + (lane<<3));
  F8 bv = ld8(b + (lane<<3));
  F8 u;
#pragma unroll
  for(int i=0;i<8;i++) u.v[i] = fmaf(t.v[i]*inv, wv.v[i], bv.v[i]);
  float s2u = wredsum(ssq8(u));
  float nu  = sqrtf(fmaxf(s2u, EPS2f));
  float se  = tanhf(nu)/nu;
#pragma unroll
  for(int i=0;i<8;i++) u.v[i] *= se;
  float s2p = wredsum(ssq8(u));
  float npn = sqrtf(fmaxf(s2p, EPS2f));
  float nc2 = fminf(fmaxf(npn, EPSf), MAXNf);
  float al  = atanhf(nc2)/nc2;
#pragma unroll
  for(int i=0;i<8;i++) u.v[i] *= al;
  st8bf(th + o, tl + o, u);
}

// t = logmap0(p) -> bf16 hi/lo
__global__ void k_logmap(const float* __restrict__ in, u16* __restrict__ th,
                         u16* __restrict__ tl){
  const int r = blockIdx.x, lane = threadIdx.x;
  const size_t o = (size_t)r*D_ + (lane<<3);
  F8 x = ld8(in + o);
  float s2 = wredsum(ssq8(x));
  float n  = sqrtf(fmaxf(s2, EPS2f));
  float nc = fminf(fmaxf(n, EPSf), MAXNf);
  float a  = atanhf(nc)/nc;
#pragma unroll
  for(int i=0;i<8;i++) x.v[i] *= a;
  st8bf(th + o, tl + o, x);
}

// sum KSG_ partials -> expmap0 -> logmap0 -> *betaS -> per-head expmap0 -> head
// layout as bf16 hi/lo. aux: mode0 q2, mode1 k2, mode2 lam-1 (V scaled by lam).
__global__ void k_split(const float* __restrict__ up, u16* __restrict__ vh,
                        u16* __restrict__ vl, float* __restrict__ aux,
                        int mode, float betaS){
  const int r = blockIdx.x, lane = threadIdx.x;
  const int b = r / S_, s = r % S_;
  const size_t o = (size_t)r*D_ + (lane<<3);
  F8 u = ld8(up + o);
  for(int ks=1; ks<KSG_; ks++){
    F8 t = ld8(up + (size_t)ks*N_*D_ + o);
#pragma unroll
    for(int i=0;i<8;i++) u.v[i] += t.v[i];
  }
  float s2u = wredsum(ssq8(u));
  float n   = sqrtf(fmaxf(s2u, EPS2f));
  float se  = tanhf(n)/n;
#pragma unroll
  for(int i=0;i<8;i++) u.v[i] *= se;
  float s2p = wredsum(ssq8(u));
  float np  = sqrtf(fmaxf(s2p, EPS2f));
  float nc  = fminf(fmaxf(np, EPSf), MAXNf);
  float al  = atanhf(nc)/nc * betaS;
#pragma unroll
  for(int i=0;i<8;i++) u.v[i] *= al;
  float s2h = g8sum(ssq8(u));
  float nh  = sqrtf(fmaxf(s2h, EPS2f));
  float sh  = tanhf(nh)/nh;
#pragma unroll
  for(int i=0;i<8;i++) u.v[i] *= sh;     // head-ball point
  const int head = lane>>3, d0 = (lane&7)<<3;
  const size_t ho = ((size_t)(b*H_+head)*S_ + s)*HD_ + d0;
  const float n2 = g8sum(ssq8(u));       // ||p_head||^2 (exact fp32)
  if (mode == 2){
    float lam = 2.f/fmaxf(1.f - n2, EPSf);
#pragma unroll
    for(int i=0;i<8;i++) u.v[i] *= lam;
    if((lane&7)==0) aux[(size_t)(b*H_+head)*S_ + s] = lam - 1.f;
  } else {
    if((lane&7)==0) aux[(size_t)(b*H_+head)*S_ + s] = n2;
  }
  st8bf(vh + ho, vl + ho, u);
}

// ---------------- MFMA attention (x32-only, ds_write staging) ----------------
// Per block (bh, qt, ks): per 64-key tile:
//  phase1: stage K + VT (reg->LDS ds_write, XOR-granule swizzle), sidecars.
//  phase2: S^T = K.Q^T per 16-key wave strip (x32 hi/lo 3-product); D-frag holds
//          [key=lhi*4+r][query=llo]; dist->exp in fp32; den partial via shfl;
//          P[q][k] written to LDS as bf16 hi/lo (packed 8B, granule-swizzled).
//  phase3: PV: wave w owns queries w*16..+15; full-64-key x32 3-product from
//          LDS P (A) and VT (B). No numerator cross-wave combine needed.
#define QH_ 0
#define QL_ 4096
#define KH_ 8192
#define KL_ 12288
#define VTH_ 16384
#define VTL_ 20480
#define PH_ 24576
#define PL_ 28672
__global__ __launch_bounds__(256) void k_attn(
    const u16* __restrict__ qhh, const u16* __restrict__ qhl,
    const u16* __restrict__ khh, const u16* __restrict__ khl,
    const u16* __restrict__ lvh, const u16* __restrict__ lvl,
    const float* __restrict__ q2a, const float* __restrict__ k2a,
    const float* __restrict__ l1a, const float* __restrict__ taup,
    const float* __restrict__ gamp, float* __restrict__ nump,
    float* __restrict__ denp){
  const int bid = blockIdx.x;
  const int bh  = bid >> 6;
  const int qt  = (bid & 63) >> 2;
  const int ks  = bid & 3;
  if ((ks<<2) > qt) return;
  __shared__ u16 SH[32768];              // 8 regions x [64][64] u16
  __shared__ float k2s[64], l1s[64], q2s[64], dden[4][64];
  const int tid  = threadIdx.x;
  const int w    = tid >> 6;
  const int lane = tid & 63;
  const int llo  = lane & 15, lhi = lane >> 4;
  const float tau = *taup, gam = *gamp;
  const size_t hbase = (size_t)bh * S_;
  // staging geometry: thread -> (row, two 8-u16 granules), XOR-swizzled by row&7
  const int srow = tid >> 2;             // 0..63
  const int sc0  = (tid & 3) << 4;       // u16 col 0/16/32/48
  const int sg0  = ((sc0 >> 3)    ) ^ (srow & 7);
  const int sg1  = ((sc0 >> 3) + 1) ^ (srow & 7);
  // ---- stage Q (once, reg->LDS) + q2 ----
  {
    const size_t qo = (hbase + (size_t)((qt<<6) + srow)) * HD_ + sc0;
    u16x8 a0 = *(const u16x8*)(qhh + qo), a1 = *(const u16x8*)(qhh + qo + 8);
    u16x8 b0 = *(const u16x8*)(qhl + qo), b1 = *(const u16x8*)(qhl + qo + 8);
    *(u16x8*)&SH[QH_ + srow*64 + (sg0<<3)] = a0;
    *(u16x8*)&SH[QH_ + srow*64 + (sg1<<3)] = a1;
    *(u16x8*)&SH[QL_ + srow*64 + (sg0<<3)] = b0;
    *(u16x8*)&SH[QL_ + srow*64 + (sg1<<3)] = b1;
    if (tid >= 128 && tid < 192) q2s[tid-128] = q2a[hbase + (qt<<6) + tid-128];
  }
  f32x4 acc[4];                          // acc[df]: queries w*16.., d df*16+llo
#pragma unroll
  for(int df=0;df<4;df++) acc[df] = (f32x4){0.f,0.f,0.f,0.f};
  float dacc[4] = {0.f,0.f,0.f,0.f};
  for(int kt=0; kt<4; kt++){
    const int j0 = (ks<<8) + (kt<<6);
    if (j0 > (qt<<6)) break;             // block-uniform
    __syncthreads();                     // prev PV reads complete
    const size_t kb = (hbase + j0) * HD_;
    { // K hi/lo rows -> KH_/KL_ (swizzled)
      const size_t ko = kb + (size_t)srow*HD_ + sc0;
      u16x8 a0 = *(const u16x8*)(khh + ko), a1 = *(const u16x8*)(khh + ko + 8);
      u16x8 b0 = *(const u16x8*)(khl + ko), b1 = *(const u16x8*)(khl + ko + 8);
      *(u16x8*)&SH[KH_ + srow*64 + (sg0<<3)] = a0;
      *(u16x8*)&SH[KH_ + srow*64 + (sg1<<3)] = a1;
      *(u16x8*)&SH[KL_ + srow*64 + (sg0<<3)] = b0;
      *(u16x8*)&SH[KL_ + srow*64 + (sg1<<3)] = b1;
    }
    { // VT[d][key], 8-u16-granule XOR swizzle: pos = (key>>3) ^ (d&7)
      const int j = tid >> 2, d0 = (tid & 3) << 4;
      const u16* sh = lvh + kb + (size_t)j*HD_ + d0;
      const u16* sl = lvl + kb + (size_t)j*HD_ + d0;
      u16x8 a0 = *(const u16x8*)sh, a1 = *(const u16x8*)(sh+8);
      u16x8 b0 = *(const u16x8*)sl, b1 = *(const u16x8*)(sl+8);
      const int jc = j >> 3, jr = j & 7;
#pragma unroll
      for(int e=0;e<8;e++){
        const int d = d0 + e;
        const int off = d*64 + ((jc ^ (d&7))<<3) + jr;
        SH[VTH_ + off] = a0[e];
        SH[VTL_ + off] = b0[e];
      }
#pragma unroll
      for(int e=0;e<8;e++){
        const int d = d0 + 8 + e;
        const int off = d*64 + ((jc ^ (d&7))<<3) + jr;
        SH[VTH_ + off] = a1[e];
        SH[VTL_ + off] = b1[e];
      }
    }
    if (tid < 64)       k2s[tid]    = k2a[hbase + j0 + tid];
    else if (tid < 128) l1s[tid-64] = l1a[hbase + j0 + tid-64];
    __syncthreads();
    // ---- S^T = K.Q^T, wave strip keys w*16..w*16+15 ----
    f32x4 sacc[4];
#pragma unroll
    for(int nf=0;nf<4;nf++) sacc[nf] = (f32x4){0.f,0.f,0.f,0.f};
#pragma unroll
    for(int kc=0;kc<2;kc++){
      const int arow = (w<<4) + llo;
      const int ach  = ((kc<<2) + lhi) ^ (llo&7);
      const s16x8 akh = *(const s16x8*)&SH[KH_ + arow*64 + (ach<<3)];
      const s16x8 akl = *(const s16x8*)&SH[KL_ + arow*64 + (ach<<3)];
#pragma unroll
      for(int nf=0;nf<4;nf++){
        const int brow = (nf<<4) + llo;
        const s16x8 bqh = *(const s16x8*)&SH[QH_ + brow*64 + (ach<<3)];
        const s16x8 bql = *(const s16x8*)&SH[QL_ + brow*64 + (ach<<3)];
        sacc[nf] = __builtin_amdgcn_mfma_f32_16x16x32_bf16(akh, bqh, sacc[nf], 0,0,0);
        sacc[nf] = __builtin_amdgcn_mfma_f32_16x16x32_bf16(akl, bqh, sacc[nf], 0,0,0);
        sacc[nf] = __builtin_amdgcn_mfma_f32_16x16x32_bf16(akh, bql, sacc[nf], 0,0,0);
      }
    }
    // ---- dist -> weight (fp32) -> P to LDS; den partials ----
    float k2v[4], omk[4], l1v[4]; int keyr[4];
#pragma unroll
    for(int r=0;r<4;r++){
      const int kk = (w<<4) + (lhi<<2) + r;
      k2v[r] = k2s[kk]; omk[r] = 1.f - k2v[r]; l1v[r] = l1s[kk]; keyr[r] = j0 + kk;
    }
    const int pgr  = (w<<1) + (lhi>>1);  // col granule (cols w*16+lhi*4+r)
    const int poff = (lhi&1) << 2;       // within-granule u16 offset
#pragma unroll
    for(int nf=0;nf<4;nf++){
      const float q2v = q2s[(nf<<4)+llo];
      const float omq = 1.f - q2v;
      const int qi = (qt<<6) + (nf<<4) + llo;
      float wv[4];
#pragma unroll
      for(int r=0;r<4;r++){
        const float dot = sacc[nf][r];
        const float d2 = fmaxf(q2v + k2v[r] - 2.f*dot, 0.f);
        const float dn = fmaxf(omq*omk[r], EPSf);
        const float z  = fmaxf(1.f + 2.f*d2/dn, 1.f + 1e-7f);
        const float dist = __logf(z + __fsqrt_rn(fmaf(z,z,-1.f)));
        wv[r] = (keyr[r] <= qi) ? __expf(fmaf(-tau, dist, -gam)) : 0.f;
      }
      float dp = (wv[0]*l1v[0] + wv[1]*l1v[1]) + (wv[2]*l1v[2] + wv[3]*l1v[3]);
      dp += __shfl_xor(dp, 16, 64);
      dp += __shfl_xor(dp, 32, 64);
      dacc[nf] += dp;
      u16 h0,l0,h1,l1,h2,l2,h3,l3;
      bfsplit(wv[0],h0,l0); bfsplit(wv[1],h1,l1);
      bfsplit(wv[2],h2,l2); bfsplit(wv[3],h3,l3);
      const int row = (nf<<4) + llo;
      const int pp  = pgr ^ (llo&7);     // row&7 == llo&7
      *(s16x4*)&SH[PH_ + row*64 + (pp<<3) + poff] =
          (s16x4){(short)h0,(short)h1,(short)h2,(short)h3};
      *(s16x4*)&SH[PL_ + row*64 + (pp<<3) + poff] =
          (s16x4){(short)l0,(short)l1,(short)l2,(short)l3};
    }
    __syncthreads();
    // ---- PV: full 64 keys, wave w owns queries w*16..w*16+15 ----
#pragma unroll
    for(int kc2=0;kc2<2;kc2++){
      const int prow = (w<<4) + llo;
      const int ach  = ((kc2<<2) + lhi) ^ (llo&7);
      const s16x8 aph = *(const s16x8*)&SH[PH_ + prow*64 + (ach<<3)];
      const s16x8 apl = *(const s16x8*)&SH[PL_ + prow*64 + (ach<<3)];
#pragma unroll
      for(int df=0;df<4;df++){
        const int vrow = (df<<4) + llo;
        const s16x8 bvh = *(const s16x8*)&SH[VTH_ + vrow*64 + (ach<<3)];
        const s16x8 bvl = *(const s16x8*)&SH[VTL_ + vrow*64 + (ach<<3)];
        acc[df] = __builtin_amdgcn_mfma_f32_16x16x32_bf16(aph, bvh, acc[df], 0,0,0);
        acc[df] = __builtin_amdgcn_mfma_f32_16x16x32_bf16(apl, bvh, acc[df], 0,0,0);
        acc[df] = __builtin_amdgcn_mfma_f32_16x16x32_bf16(aph, bvl, acc[df], 0,0,0);
      }
    }
  }
  // ---- den cross-wave combine + output ----
  __syncthreads();
  if (lhi == 0){
#pragma unroll
    for(int nf=0;nf<4;nf++) dden[w][(nf<<4)+llo] = dacc[nf];
  }
  __syncthreads();
  const size_t nb = ((size_t)ks*BHS_ + hbase + (size_t)(qt<<6))*HD_;
#pragma unroll
  for(int df=0;df<4;df++)
#pragma unroll
    for(int r=0;r<4;r++){
      const int q = (w<<4) + (lhi<<2) + r;
      nump[nb + (size_t)q*HD_ + (df<<4) + llo] = acc[df][r];
    }
  if (lhi == 0){
    const int i = (w<<4) + llo;
    denp[(size_t)ks*BHS_ + hbase + (qt<<6) + i]
      = dden[0][i] + dden[1][i] + dden[2][i] + dden[3][i];
  }
}

// combine key-split partials -> midpoint -> 0.5-scalar-mul -> project -> beta-concat
__global__ void k_combine(const float* __restrict__ nump, const float* __restrict__ denp,
                          float* __restrict__ pout, float betaC){
  const int r = blockIdx.x, lane = threadIdx.x;
  const int b = r / S_, s = r % S_;
  const int nks  = (s >> 8) + 1;
  const int head = lane >> 3;
  const int d0   = (lane & 7) << 3;
  const size_t hrow = (size_t)(b*H_ + head)*S_ + s;
  F8 num;
#pragma unroll
  for(int i=0;i<8;i++) num.v[i]=0.f;
  float den = 0.f;
  for(int ks=0; ks<nks; ks++){
    F8 t = ld8(nump + ((size_t)ks*BHS_ + hrow)*HD_ + d0);
#pragma unroll
    for(int i=0;i<8;i++) num.v[i] += t.v[i];
    den += denp[(size_t)ks*BHS_ + hrow];
  }
  den = fmaxf(den, EPSf);
  F8 y;
#pragma unroll
  for(int i=0;i<8;i++) y.v[i] = num.v[i]/den;
  float s2 = g8sum(ssq8(y));
  float n  = fminf(fmaxf(sqrtf(fmaxf(s2,EPS2f)), EPSf), MAXNf);
  float ms = tanhf(0.5f*atanhf(n))/n;
#pragma unroll
  for(int i=0;i<8;i++) y.v[i] *= ms;
  float s2y = g8sum(ssq8(y));
  float ny  = sqrtf(fmaxf(s2y, EPS2f));
  float pf  = fminf(1.f, MAXNf/ny);
#pragma unroll
  for(int i=0;i<8;i++) y.v[i] *= pf;
  float s2c = g8sum(ssq8(y));
  float np2 = sqrtf(fmaxf(s2c, EPS2f));
  float ncc = fminf(fmaxf(np2, EPSf), MAXNf);
  float al  = atanhf(ncc)/ncc * betaC;
#pragma unroll
  for(int i=0;i<8;i++) y.v[i] *= al;
  float s2t = wredsum(ssq8(y));
  float nt  = sqrtf(fmaxf(s2t, EPS2f));
  float se  = tanhf(nt)/nt;
#pragma unroll
  for(int i=0;i<8;i++) y.v[i] *= se;
  st8(pout + (size_t)r*D_ + head*HD_ + d0, y);
}

// FFN middle: sum 2 partials -> expmap -> logmap -> relu -> expmap -> logmap -> bf16 hi/lo
__global__ void k_ffn_mid(const float* __restrict__ u, u16* __restrict__ th,
                          u16* __restrict__ tl){
  const int r = blockIdx.x, lane = threadIdx.x;
  const float* p0 = u + (size_t)r*FF_ + (lane<<5);
  const float* p1 = p0 + (size_t)N_*FF_;
  float4 x[8];
#pragma unroll
  for(int c=0;c<8;c++){
    float4 a = *(const float4*)(p0 + (c<<2));
    float4 b = *(const float4*)(p1 + (c<<2));
    x[c] = make_float4(a.x+b.x, a.y+b.y, a.z+b.z, a.w+b.w);
  }
  float ls;
#define SSQ8x4(out) { out=0.f; _Pragma("unroll") for(int c=0;c<8;c++){ out=fmaf(x[c].x,x[c].x,out); out=fmaf(x[c].y,x[c].y,out); out=fmaf(x[c].z,x[c].z,out); out=fmaf(x[c].w,x[c].w,out);} }
#define SCALE8x4(a) { _Pragma("unroll") for(int c=0;c<8;c++){ x[c].x*=(a); x[c].y*=(a); x[c].z*=(a); x[c].w*=(a);} }
  SSQ8x4(ls);
  float s2 = wredsum(ls);
  float n  = sqrtf(fmaxf(s2, EPS2f));
  SCALE8x4(tanhf(n)/n);
  SSQ8x4(ls); s2 = wredsum(ls);
  n = sqrtf(fmaxf(s2, EPS2f));
  float nc = fminf(fmaxf(n, EPSf), MAXNf);
  SCALE8x4(atanhf(nc)/nc);
#pragma unroll
  for(int c=0;c<8;c++){
    x[c].x=fmaxf(x[c].x,0.f); x[c].y=fmaxf(x[c].y,0.f);
    x[c].z=fmaxf(x[c].z,0.f); x[c].w=fmaxf(x[c].w,0.f);
  }
  SSQ8x4(ls); s2 = wredsum(ls);
  n = sqrtf(fmaxf(s2, EPS2f));
  SCALE8x4(tanhf(n)/n);
  SSQ8x4(ls); s2 = wredsum(ls);
  n = sqrtf(fmaxf(s2, EPS2f));
  nc = fminf(fmaxf(n, EPSf), MAXNf);
  SCALE8x4(atanhf(nc)/nc);
  u16* hp = th + (size_t)r*FF_ + (lane<<5);
  u16* lp = tl + (size_t)r*FF_ + (lane<<5);
#pragma unroll
  for(int cc=0; cc<4; cc++){
    F8 f;
    f.v[0]=x[2*cc].x; f.v[1]=x[2*cc].y; f.v[2]=x[2*cc].z; f.v[3]=x[2*cc].w;
    f.v[4]=x[2*cc+1].x; f.v[5]=x[2*cc+1].y; f.v[6]=x[2*cc+1].z; f.v[7]=x[2*cc+1].w;
    st8bf(hp + (cc<<3), lp + (cc<<3), f);
  }
#undef SSQ8x4
#undef SCALE8x4
}

__global__ void k_final(const float* __restrict__ up, float* __restrict__ out){
  const int r = blockIdx.x, lane = threadIdx.x;
  const size_t o = (size_t)r*D_ + (lane<<3);
  F8 u = ld8(up + o);
  for(int ks=1; ks<KSG_; ks++){
    F8 t = ld8(up + (size_t)ks*N_*D_ + o);
#pragma unroll
    for(int i=0;i<8;i++) u.v[i] += t.v[i];
  }
  float s2 = wredsum(ssq8(u));
  float n  = sqrtf(fmaxf(s2, EPS2f));
  float se = tanhf(n)/n;
#pragma unroll
  for(int i=0;i<8;i++) u.v[i] *= se;
  st8(out + o, u);
}

// ---------------- weight conversion ----------------
__global__ void k_cvt6(const float* __restrict__ Wq, const float* __restrict__ Wk,
                       const float* __restrict__ Wv, const float* __restrict__ Wo,
                       const float* __restrict__ W1, const float* __restrict__ W2,
                       u16* __restrict__ wb){
  const int t = blockIdx.y;
  const int n = (t<4) ? (D_*D_) : (FF_*D_);
  const int idx = (int)((blockIdx.x*256 + threadIdx.x)<<3);
  if (idx >= n) return;
  const float* src; u16 *hp, *lp;
  switch(t){
    case 0: src=Wq; hp=wb;          lp=wb+262144;  break;
    case 1: src=Wk; hp=wb+524288;   lp=wb+786432;  break;
    case 2: src=Wv; hp=wb+1048576;  lp=wb+1310720; break;
    case 3: src=Wo; hp=wb+1572864;  lp=wb+1835008; break;
    case 4: src=W1; hp=wb+2097152;  lp=wb+3145728; break;
    default:src=W2; hp=wb+4194304;  lp=wb+5242880; break;
  }
  cvt8(src+idx, hp+idx, lp+idx);
}
__global__ void k_cvt1(const float* __restrict__ src, u16* __restrict__ hp,
                       u16* __restrict__ lp){
  const int idx = (int)((blockIdx.x*256 + threadIdx.x)<<3);
  cvt8(src+idx, hp+idx, lp+idx);
}

// ---------------- MFMA GEMM (unchanged, round-4-proven) ----------------
#define SAH 0
#define SAL 8192
#define SWH 16384
#define SWL 24576
__global__ __launch_bounds__(256) void k_gemm_mfma(
    const u16* __restrict__ Ah, const u16* __restrict__ Al,
    const u16* __restrict__ Wh, const u16* __restrict__ Wl,
    const float* __restrict__ bias, float* __restrict__ C,
    int K, int M, int kslen){
  __shared__ u16 lds[32768];
  const int tid = threadIdx.x;
  const int wv = tid>>6, lane = tid&63;
  const int wr = wv>>1, wc = wv&1;
  const int lhi = lane>>4, llo = lane&15;
  const int m0 = blockIdx.x<<7;
  const int n0 = blockIdx.y<<7;
  const int ks = blockIdx.z;
  f32x4 acc[4][4];
#pragma unroll
  for(int i=0;i<4;i++)
#pragma unroll
    for(int j=0;j<4;j++) acc[i][j] = (f32x4){0.f,0.f,0.f,0.f};
  const int sr = lane>>3;
  const int g  = (lane&7) ^ sr;
  const int kend = (ks+1)*kslen;
  for(int k0 = ks*kslen; k0 < kend; k0 += 64){
    __syncthreads();
#pragma unroll
    for(int t=0;t<4;t++){
      const int row = wv*32 + t*8 + sr;
      const int lo  = (wv*4+t)*512;
      const size_t ga = (size_t)(n0+row)*K + k0 + g*8;
      const size_t gw = (size_t)(m0+row)*K + k0 + g*8;
      gll16(Ah + ga, &lds[SAH+lo]);
      gll16(Al + ga, &lds[SAL+lo]);
      gll16(Wh + gw, &lds[SWH+lo]);
      gll16(Wl + gw, &lds[SWL+lo]);
    }
    __syncthreads();
#pragma unroll
    for(int kc=0;kc<2;kc++){
      s16x8 ah[4], al4[4], wh4[4], wl4[4];
#pragma unroll
      for(int f=0;f<4;f++){
        const int ra = wr*64 + f*16 + llo;
        const int rw = wc*64 + f*16 + llo;
        const int ca = (kc*4 + lhi) ^ (llo&7);
        ah[f]  = *(const s16x8*)&lds[SAH + ra*64 + ca*8];
        al4[f] = *(const s16x8*)&lds[SAL + ra*64 + ca*8];
        wh4[f] = *(const s16x8*)&lds[SWH + rw*64 + ca*8];
        wl4[f] = *(const s16x8*)&lds[SWL + rw*64 + ca*8];
      }
#pragma unroll
      for(int i=0;i<4;i++)
#pragma unroll
        for(int j=0;j<4;j++){
          acc[i][j] = __builtin_amdgcn_mfma_f32_16x16x32_bf16(ah[i],  wh4[j], acc[i][j], 0,0,0);
          acc[i][j] = __builtin_amdgcn_mfma_f32_16x16x32_bf16(ah[i],  wl4[j], acc[i][j], 0,0,0);
          acc[i][j] = __builtin_amdgcn_mfma_f32_16x16x32_bf16(al4[i], wh4[j], acc[i][j], 0,0,0);
        }
    }
  }
  const size_t cbase = (size_t)ks*(size_t)N_*M;
  float bload[4];
#pragma unroll
  for(int j=0;j<4;j++)
    bload[j] = (ks==0) ? bias[m0 + wc*64 + j*16 + llo] : 0.f;
#pragma unroll
  for(int i=0;i<4;i++)
#pragma unroll
    for(int r=0;r<4;r++){
      const int n = n0 + wr*64 + i*16 + lhi*4 + r;
      float* cp = C + cbase + (size_t)n*M + m0 + wc*64 + llo;
#pragma unroll
      for(int j=0;j<4;j++) cp[j*16] = acc[i][j][r] + bload[j];
    }
}

// ---------------- host ----------------
extern "C" void kernel_launch(void* const* d_in, const int* in_sizes, int n_in,
                              void* d_out, int out_size, void* d_ws, size_t ws_size,
                              hipStream_t stream){
  const float* x_in = (const float*)d_in[0];
  const float* pos  = (const float*)d_in[1];
  const float* ln1w = (const float*)d_in[2];
  const float* ln1b = (const float*)d_in[3];
  const float* ln2w = (const float*)d_in[4];
  const float* ln2b = (const float*)d_in[5];
  const float* Wq   = (const float*)d_in[6];
  const float* bq   = (const float*)d_in[7];
  const float* Wk   = (const float*)d_in[8];
  const float* bk   = (const float*)d_in[9];
  const float* Wv   = (const float*)d_in[10];
  const float* bv   = (const float*)d_in[11];
  const float* Wo   = (const float*)d_in[12];
  const float* bo   = (const float*)d_in[13];
  const float* W1   = (const float*)d_in[14];
  const float* b1   = (const float*)d_in[15];
  const float* W2   = (const float*)d_in[16];
  const float* b2   = (const float*)d_in[17];
  const float* tau  = (const float*)d_in[18];
  const float* gam  = (const float*)d_in[19];
  const float* Wout = (const float*)d_in[20];
  const float* bout = (const float*)d_in[21];

  float* ws = (float*)d_ws;
  float* xb  = ws;                               // [N,D] fp32
  float* ub  = xb  + (size_t)N_*D_;              // [8,N,512]/[2,N,2048] partials; nump alias
  float* q2b = ub  + (size_t)KSG_*N_*D_;         // [B,H,S]
  float* k2b = q2b + BHS_;                       // [B,H,S]
  float* l1b = k2b + BHS_;                       // [B,H,S]
  float* dnb = l1b + BHS_;                       // [KSA,B,H,S]
  u16*   tbh = (u16*)(dnb + (size_t)KSA_*BHS_);  // [N,FF] bf16 hi
  u16*   tbl = tbh + (size_t)N_*FF_;             // [N,FF] bf16 lo
  u16*   wb  = tbl + (size_t)N_*FF_;             // weight hi/lo arena
  u16*   qhh = wb  + 6291456;                    // [B,H,S,HD] x6 bf16
  u16*   qhl = qhh + (size_t)N_*D_;
  u16*   khh = qhl + (size_t)N_*D_;
  u16*   khl = khh + (size_t)N_*D_;
  u16*   lvh = khl + (size_t)N_*D_;
  u16*   lvl = lvh + (size_t)N_*D_;
  float* nump = ub;                              // KSA*BHS*HD = 4M floats
  float* patt = ub + (size_t)KSA_*BHS_*HD_;      // 1M floats, inside ub tail

  const double bd  = exp(lgamma(D_/2.0)  + lgamma(0.5) - lgamma(D_/2.0  + 0.5));
  const double bhd = exp(lgamma(HD_/2.0) + lgamma(0.5) - lgamma(HD_/2.0 + 0.5));
  const float betaS = (float)(bhd/bd);
  const float betaC = (float)(bd/bhd);

  const dim3 g512(4, 16, KSG_);
  const dim3 gff1(16, 16, KSF_);
  const dim3 gcv(512, 6);

  k_mobius_pos<<<N_,64,0,stream>>>(x_in, pos, xb);
  for(int l=0; l<L_; l++){
    k_cvt6<<<gcv,256,0,stream>>>(Wq + (size_t)l*D_*D_, Wk + (size_t)l*D_*D_,
                                 Wv + (size_t)l*D_*D_, Wo + (size_t)l*D_*D_,
                                 W1 + (size_t)l*FF_*D_, W2 + (size_t)l*D_*FF_, wb);
    k_pln_tan<<<N_,64,0,stream>>>(xb, ln1w + l*D_, ln1b + l*D_, tbh, tbl);
    k_gemm_mfma<<<g512,256,0,stream>>>(tbh, tbl, wb,          wb+262144,  bq + l*D_, ub, 512, 512, 64);
    k_split<<<N_,64,0,stream>>>(ub, qhh, qhl, q2b, 0, betaS);
    k_gemm_mfma<<<g512,256,0,stream>>>(tbh, tbl, wb+524288,   wb+786432,  bk + l*D_, ub, 512, 512, 64);
    k_split<<<N_,64,0,stream>>>(ub, khh, khl, k2b, 1, betaS);
    k_gemm_mfma<<<g512,256,0,stream>>>(tbh, tbl, wb+1048576,  wb+1310720, bv + l*D_, ub, 512, 512, 64);
    k_split<<<N_,64,0,stream>>>(ub, lvh, lvl, l1b, 2, betaS);
    k_attn<<<1024,256,0,stream>>>(qhh, qhl, khh, khl, lvh, lvl,
                                  q2b, k2b, l1b, tau + l, gam + l, nump, dnb);
    k_combine<<<N_,64,0,stream>>>(nump, dnb, patt, betaC);
    k_logmap<<<N_,64,0,stream>>>(patt, tbh, tbl);
    k_gemm_mfma<<<g512,256,0,stream>>>(tbh, tbl, wb+1572864,  wb+1835008, bo + l*D_, ub, 512, 512, 64);
    k_mobius_epi<<<N_,64,0,stream>>>(ub, xb);
    k_pln_tan<<<N_,64,0,stream>>>(xb, ln2w + l*D_, ln2b + l*D_, tbh, tbl);
    k_gemm_mfma<<<gff1,256,0,stream>>>(tbh, tbl, wb+2097152,  wb+3145728, b1 + l*FF_, ub, 512, 2048, 256);
    k_ffn_mid<<<N_,64,0,stream>>>(ub, tbh, tbl);
    k_gemm_mfma<<<g512,256,0,stream>>>(tbh, tbl, wb+4194304,  wb+5242880, b2 + l*D_, ub, 2048, 512, 256);
    k_mobius_epi<<<N_,64,0,stream>>>(ub, xb);
  }
  k_logmap<<<N_,64,0,stream>>>(xb, tbh, tbl);
  k_cvt1<<<128,256,0,stream>>>(Wout, wb, wb+262144);
  k_gemm_mfma<<<g512,256,0,stream>>>(tbh, tbl, wb, wb+262144, bout, ub, 512, 512, 64);
  k_final<<<N_,64,0,stream>>>(ub, (float*)d_out);
}